// Round 7
// baseline (619.697 us; speedup 1.0000x reference)
//
#include <hip/hip_runtime.h>

#define D_ 768
#define S_ 512
#define R_ 512
#define L_ 103
#define F_ 4
#define NACCU 119
#define NTERM 11

using short8  = __attribute__((ext_vector_type(8))) short;
using short4v = __attribute__((ext_vector_type(4))) short;
using f32x4   = __attribute__((ext_vector_type(4))) float;

__device__ __forceinline__ short f2bf(float x){
  unsigned u = __float_as_uint(x);
  unsigned r = (u + 0x7FFFu + ((u >> 16) & 1u)) >> 16;  // RNE
  return (short)r;
}

// async global->LDS, 16B per lane (global_load_lds_dwordx4)
__device__ __forceinline__ void gload16(const short* g, short* l){
  __builtin_amdgcn_global_load_lds(
      (const __attribute__((address_space(1))) void*)g,
      (__attribute__((address_space(3))) void*)l, 16, 0, 0);
}

#define SFENCE() __builtin_amdgcn_sched_barrier(0)
#define BAR()    __builtin_amdgcn_s_barrier()

// ---------------- K1: u = Wv^T w_dprob, v2 = Wk^T bq, c = bv.w_dprob ----------------
__global__ void k_prep(const float* __restrict__ Wv, const float* __restrict__ wd,
                       const float* __restrict__ Wk, const float* __restrict__ bq,
                       const float* __restrict__ bv,
                       float* __restrict__ u, float* __restrict__ v2, float* __restrict__ cw){
  int tid = threadIdx.x;
  if (blockIdx.x < 3){
    int d = blockIdx.x * 256 + tid;
    float su = 0.f, sv = 0.f;
    #pragma unroll 8
    for (int e = 0; e < D_; ++e){
      su = fmaf(Wv[e * D_ + d], wd[e], su);
      sv = fmaf(Wk[e * D_ + d], bq[e], sv);
    }
    u[d] = su; v2[d] = sv;
  } else {
    __shared__ float red[256];
    float p = bv[tid] * wd[tid] + bv[tid + 256] * wd[tid + 256] + bv[tid + 512] * wd[tid + 512];
    red[tid] = p;
    __syncthreads();
    for (int s = 128; s > 0; s >>= 1){
      if (tid < s) red[tid] += red[tid + s];
      __syncthreads();
    }
    if (tid == 0) cw[0] = red[0];
  }
}

// Shared MFMA inner step (used by fallback + small GEMMs)
__device__ __forceinline__ void mfma_tile(const short* As, const short* Bs, f32x4 (&acc)[4][4],
                                          int wr, int wc, int ln, int lh){
  #pragma unroll
  for (int half = 0; half < 2; ++half){
    short8 a[4], b[4];
    #pragma unroll
    for (int i = 0; i < 4; ++i){
      int row = wr * 64 + i * 16 + ln;
      int ch = (lh + half * 4) ^ (row & 7);
      a[i] = *reinterpret_cast<const short8*>(&As[row * 64 + ch * 8]);
    }
    #pragma unroll
    for (int j = 0; j < 4; ++j){
      int row = wc * 64 + j * 16 + ln;
      int ch = (lh + half * 4) ^ (row & 7);
      b[j] = *reinterpret_cast<const short8*>(&Bs[row * 64 + ch * 8]);
    }
    #pragma unroll
    for (int i = 0; i < 4; ++i)
      #pragma unroll
      for (int j = 0; j < 4; ++j)
        acc[i][j] = __builtin_amdgcn_mfma_f32_16x16x32_bf16(a[i], b[j], acc[i][j], 0, 0, 0);
  }
}

// ---------------- K2: Mt[d',d] = sum_e Wk[e,d'] * Wq[e,d]  (bf16 out, linear) ----------------
__global__ __launch_bounds__(256) void k_gemm_M(const float* __restrict__ Wk, const float* __restrict__ Wq,
                                                short* __restrict__ Mt){
  __shared__ __align__(16) short As[128 * 64];
  __shared__ __align__(16) short Bs[128 * 64];
  int bid = blockIdx.x;
  int m0 = (bid / 6) * 128, n0 = (bid % 6) * 128;
  int tid = threadIdx.x, lane = tid & 63, wid = tid >> 6;
  int wr = wid >> 1, wc = wid & 1, ln = lane & 15, lh = lane >> 4;
  f32x4 acc[4][4];
  #pragma unroll
  for (int i = 0; i < 4; ++i)
    #pragma unroll
    for (int j = 0; j < 4; ++j)
      acc[i][j] = (f32x4){0.f, 0.f, 0.f, 0.f};
  int mm = (tid & 31) * 4;
  int kb = tid >> 5;   // 0..7
  for (int k0 = 0; k0 < D_; k0 += 64){
    #pragma unroll
    for (int ki = 0; ki < 8; ++ki){
      int k = kb + ki * 8;
      float4 va = *reinterpret_cast<const float4*>(&Wk[(k0 + k) * D_ + m0 + mm]);
      float4 vb = *reinterpret_cast<const float4*>(&Wq[(k0 + k) * D_ + n0 + mm]);
      As[(mm + 0) * 64 + ((ki ^ ((mm + 0) & 7)) * 8) + kb] = f2bf(va.x);
      As[(mm + 1) * 64 + ((ki ^ ((mm + 1) & 7)) * 8) + kb] = f2bf(va.y);
      As[(mm + 2) * 64 + ((ki ^ ((mm + 2) & 7)) * 8) + kb] = f2bf(va.z);
      As[(mm + 3) * 64 + ((ki ^ ((mm + 3) & 7)) * 8) + kb] = f2bf(va.w);
      Bs[(mm + 0) * 64 + ((ki ^ ((mm + 0) & 7)) * 8) + kb] = f2bf(vb.x);
      Bs[(mm + 1) * 64 + ((ki ^ ((mm + 1) & 7)) * 8) + kb] = f2bf(vb.y);
      Bs[(mm + 2) * 64 + ((ki ^ ((mm + 2) & 7)) * 8) + kb] = f2bf(vb.z);
      Bs[(mm + 3) * 64 + ((ki ^ ((mm + 3) & 7)) * 8) + kb] = f2bf(vb.w);
    }
    __syncthreads();
    mfma_tile(As, Bs, acc, wr, wc, ln, lh);
    __syncthreads();
  }
  #pragma unroll
  for (int i = 0; i < 4; ++i)
    #pragma unroll
    for (int j = 0; j < 4; ++j)
      #pragma unroll
      for (int rg = 0; rg < 4; ++rg){
        int row = m0 + wr * 64 + i * 16 + lh * 4 + rg;
        int col = n0 + wc * 64 + j * 16 + ln;
        Mt[row * D_ + col] = f2bf(acc[i][j][rg]);
      }
}

// ---------------- K3: G[t,d'] = sum_d fact[t,d] * Mt[d',d]  (bf16 out, LINEAR) ----------------
__global__ __launch_bounds__(256) void k_gemm_G(const float* __restrict__ A, const short* __restrict__ Mt,
                                                short* __restrict__ Gb){
  __shared__ __align__(16) short As[128 * 64];
  __shared__ __align__(16) short Bs[128 * 64];
  int bid = blockIdx.x;
  int m0 = (bid / 6) * 128, n0 = (bid % 6) * 128;
  int tid = threadIdx.x, lane = tid & 63, wid = tid >> 6;
  int wr = wid >> 1, wc = wid & 1, ln = lane & 15, lh = lane >> 4;
  f32x4 acc[4][4];
  #pragma unroll
  for (int i = 0; i < 4; ++i)
    #pragma unroll
    for (int j = 0; j < 4; ++j)
      acc[i][j] = (f32x4){0.f, 0.f, 0.f, 0.f};
  int srow = tid >> 1, hf = tid & 1;
  int swz = srow & 7;
  const float* ap = A  + (size_t)(m0 + srow) * D_;
  const short* bp = Mt + (size_t)(n0 + srow) * D_;
  for (int k0 = 0; k0 < D_; k0 += 64){
    #pragma unroll
    for (int q = 0; q < 8; ++q){
      int k = hf * 32 + q * 4;
      float4 v = *reinterpret_cast<const float4*>(&ap[k0 + k]);
      short4v p; p[0] = f2bf(v.x); p[1] = f2bf(v.y); p[2] = f2bf(v.z); p[3] = f2bf(v.w);
      *reinterpret_cast<short4v*>(&As[srow * 64 + (((k >> 3) ^ swz) * 8) + (k & 7)]) = p;
    }
    #pragma unroll
    for (int q = 0; q < 4; ++q){
      int k = hf * 32 + q * 8;
      short8 v = *reinterpret_cast<const short8*>(&bp[k0 + k]);
      *reinterpret_cast<short8*>(&Bs[srow * 64 + (((k >> 3) ^ swz) * 8)]) = v;
    }
    __syncthreads();
    mfma_tile(As, Bs, acc, wr, wc, ln, lh);
    __syncthreads();
  }
  #pragma unroll
  for (int i = 0; i < 4; ++i)
    #pragma unroll
    for (int j = 0; j < 4; ++j)
      #pragma unroll
      for (int rg = 0; rg < 4; ++rg){
        int row = m0 + wr * 64 + i * 16 + lh * 4 + rg;
        int col = n0 + wc * 64 + j * 16 + ln;
        Gb[row * D_ + col] = f2bf(acc[i][j][rg]);
      }
}

// ---------------- K4: vw[l,r], colbias[l,r]; E->bf16 PRE-SWIZZLED (2-row ILP) ----------------
__global__ __launch_bounds__(256) void k_lawprep(const float* __restrict__ E, const float* __restrict__ u,
      const float* __restrict__ v2, const float* __restrict__ cw, const float* __restrict__ mask,
      float* __restrict__ vw, float* __restrict__ cb, short* __restrict__ ebf){
  int lane = threadIdx.x & 63;
  int w  = (blockIdx.x * blockDim.x + threadIdx.x) >> 6;
  int nw = (gridDim.x * blockDim.x) >> 6;
  float uu[12], vv[12];
  #pragma unroll
  for (int i = 0; i < 3; ++i){
    float4 a = *reinterpret_cast<const float4*>(&u[i * 256 + lane * 4]);
    float4 b = *reinterpret_cast<const float4*>(&v2[i * 256 + lane * 4]);
    uu[i*4+0] = a.x; uu[i*4+1] = a.y; uu[i*4+2] = a.z; uu[i*4+3] = a.w;
    vv[i*4+0] = b.x; vv[i*4+1] = b.y; vv[i*4+2] = b.z; vv[i*4+3] = b.w;
  }
  float c = cw[0];
  const float invsq = 0.03608439182435161f;
  int mid = (lane >> 1) & 7;
  int lo  = (lane & 1) * 4;
  int chiB = lane >> 4;
  for (int row = w * 2; row < L_ * R_; row += nw * 2){
    const float* e0 = E + (size_t)row * D_;
    const float* e1 = e0 + D_;
    int rs0 = row & 7, rs1 = (row + 1) & 7;
    float s1a = 0.f, s2a = 0.f, s1b = 0.f, s2b = 0.f;
    #pragma unroll
    for (int i = 0; i < 3; ++i){
      float4 ev0 = *reinterpret_cast<const float4*>(&e0[i * 256 + lane * 4]);
      float4 ev1 = *reinterpret_cast<const float4*>(&e1[i * 256 + lane * 4]);
      s1a = fmaf(ev0.x, uu[i*4+0], fmaf(ev0.y, uu[i*4+1], fmaf(ev0.z, uu[i*4+2], fmaf(ev0.w, uu[i*4+3], s1a))));
      s2a = fmaf(ev0.x, vv[i*4+0], fmaf(ev0.y, vv[i*4+1], fmaf(ev0.z, vv[i*4+2], fmaf(ev0.w, vv[i*4+3], s2a))));
      s1b = fmaf(ev1.x, uu[i*4+0], fmaf(ev1.y, uu[i*4+1], fmaf(ev1.z, uu[i*4+2], fmaf(ev1.w, uu[i*4+3], s1b))));
      s2b = fmaf(ev1.x, vv[i*4+0], fmaf(ev1.y, vv[i*4+1], fmaf(ev1.z, vv[i*4+2], fmaf(ev1.w, vv[i*4+3], s2b))));
      if (ebf){
        short4v p0, p1;
        p0[0] = f2bf(ev0.x); p0[1] = f2bf(ev0.y); p0[2] = f2bf(ev0.z); p0[3] = f2bf(ev0.w);
        p1[0] = f2bf(ev1.x); p1[1] = f2bf(ev1.y); p1[2] = f2bf(ev1.z); p1[3] = f2bf(ev1.w);
        int chi = i * 4 + chiB;
        *reinterpret_cast<short4v*>(&ebf[(size_t)row * D_ + chi * 64 + ((mid ^ rs0) << 3) + lo]) = p0;
        *reinterpret_cast<short4v*>(&ebf[(size_t)(row + 1) * D_ + chi * 64 + ((mid ^ rs1) << 3) + lo]) = p1;
      }
    }
    #pragma unroll
    for (int st = 1; st < 64; st <<= 1){
      s1a += __shfl_xor(s1a, st, 64);
      s2a += __shfl_xor(s2a, st, 64);
      s1b += __shfl_xor(s1b, st, 64);
      s2b += __shfl_xor(s2b, st, 64);
    }
    if (lane == 0){
      vw[row] = s1a + c;
      cb[row] = fmaf(s2a, invsq, mask[row]);
      vw[row + 1] = s1b + c;
      cb[row + 1] = fmaf(s2b, invsq, mask[row + 1]);
    }
  }
}

// ---------------- K5 v3: B-only LDS (3-buf), A direct L2->reg, 1 barrier/K-tile ----------------
// Ledger (per tile t, steady): issue {STG_B(t+2):4, A03(t+1):8, A47(t+1):8} after entry SFENCE;
// end-of-tile vmcnt(20) retires the oldest 4 = STG_B(t+1) (issued last tile, pinned older by
// asm/fences) => B(t+1) in LDS before BAR. 3-deep B buffer: STG_B(t+2) writes buf[(t+2)%3],
// never aliasing b(t) reads (buf[t%3]) or b(t-1) (completed before last BAR). A-load->MFMA
// waits are compiler-managed (data deps through a03/a47 variables).
__global__ __launch_bounds__(512, 2) void k_attn8(const short* __restrict__ Gb,
      const short* __restrict__ Ebf, const float* __restrict__ vw, const float* __restrict__ cbg,
      float* __restrict__ Zp, float* __restrict__ Wp){
  __shared__ __align__(16) short Bs[3][16384];     // 3 x [256][64] bf16 = 96 KB
  int b0 = blockIdx.x;
  int bid = (b0 & 7) * 206 + (b0 >> 3);            // 1648 = 8*206, bijective
  int l  = bid >> 4;
  int mt = (bid >> 1) & 7;
  int nt = bid & 1;
  int m0 = mt * 256, n0 = nt * 256;
  int tid = threadIdx.x, lane = tid & 63, wid = tid >> 6;
  int wr = wid >> 2, wc = wid & 3, ln = lane & 15, lh = lane >> 4;
  int c0 = tid, c1 = tid + 512;
  const short* gB0 = Ebf + (size_t)(l * R_ + n0 + (c0 >> 3)) * D_ + (c0 & 7) * 8;
  const short* gB1 = Ebf + (size_t)(l * R_ + n0 + (c1 >> 3)) * D_ + (c1 & 7) * 8;
  const short* gA  = Gb  + (size_t)(m0 + wr * 128 + ln) * D_ + lh * 8;

  f32x4 acc[8][4];
  #pragma unroll
  for (int i = 0; i < 8; ++i)
    #pragma unroll
    for (int j = 0; j < 4; ++j)
      acc[i][j] = (f32x4){0.f, 0.f, 0.f, 0.f};
  short8 a03[2][4], a47[2][4];

  #define STG_B(t) { short* d_ = &Bs[(t) % 3][0]; \
    gload16(gB0 + (t) * 64, d_ + c0 * 8); \
    gload16(gB1 + (t) * 64, d_ + c1 * 8); \
    gload16(gB0 + (size_t)128 * D_ + (t) * 64, d_ + 8192 + c0 * 8); \
    gload16(gB1 + (size_t)128 * D_ + (t) * 64, d_ + 8192 + c1 * 8); }
  #define LD_A03(t) { _Pragma("unroll") for (int ks = 0; ks < 2; ++ks) \
    _Pragma("unroll") for (int mi = 0; mi < 4; ++mi) \
      a03[ks][mi] = *reinterpret_cast<const short8*>(gA + (size_t)mi * 16 * D_ + (t) * 64 + ks * 32); }
  #define LD_A47(t) { _Pragma("unroll") for (int ks = 0; ks < 2; ++ks) \
    _Pragma("unroll") for (int mi = 0; mi < 4; ++mi) \
      a47[ks][mi] = *reinterpret_cast<const short8*>(gA + (size_t)(mi + 4) * 16 * D_ + (t) * 64 + ks * 32); }

  // prologue: B(0), B(1) staged (order-pinned), A(0) in flight
  STG_B(0); SFENCE();
  STG_B(1); SFENCE();
  LD_A03(0); LD_A47(0);
  asm volatile("s_waitcnt vmcnt(20)" ::: "memory");   // B(0) landed
  BAR(); SFENCE();

  #pragma unroll
  for (int t = 0; t < 12; ++t){
    if (t + 2 < 12) STG_B(t + 2);
    // b-frag reads from Bs[t%3] (fine-grained compiler lgkm waits; no block lockstep)
    const short* Bsl = Bs[t % 3];
    short8 bfr[2][4];
    #pragma unroll
    for (int ks = 0; ks < 2; ++ks)
      #pragma unroll
      for (int nj = 0; nj < 4; ++nj){
        int row = wc * 64 + nj * 16 + ln;
        int ch = (ks * 4 + lh) ^ (row & 7);
        bfr[ks][nj] = *reinterpret_cast<const short8*>(&Bsl[row * 64 + ch * 8]);
      }
    __builtin_amdgcn_s_setprio(1);
    #pragma unroll
    for (int ks = 0; ks < 2; ++ks)
      #pragma unroll
      for (int mi = 0; mi < 4; ++mi)
        #pragma unroll
        for (int nj = 0; nj < 4; ++nj)
          acc[mi][nj] = __builtin_amdgcn_mfma_f32_16x16x32_bf16(a03[ks][mi], bfr[ks][nj], acc[mi][nj], 0, 0, 0);
    __builtin_amdgcn_s_setprio(0);
    if (t + 1 < 12) LD_A03(t + 1);
    __builtin_amdgcn_s_setprio(1);
    #pragma unroll
    for (int ks = 0; ks < 2; ++ks)
      #pragma unroll
      for (int mi = 0; mi < 4; ++mi)
        #pragma unroll
        for (int nj = 0; nj < 4; ++nj)
          acc[mi + 4][nj] = __builtin_amdgcn_mfma_f32_16x16x32_bf16(a47[ks][mi], bfr[ks][nj], acc[mi + 4][nj], 0, 0, 0);
    __builtin_amdgcn_s_setprio(0);
    if (t + 1 < 12) LD_A47(t + 1);
    if (t < 10)       { asm volatile("s_waitcnt vmcnt(20)" ::: "memory"); }   // B(t+1) landed
    else if (t == 10) { asm volatile("s_waitcnt vmcnt(16)" ::: "memory"); }   // B(11) landed
    if (t < 11){ BAR(); SFENCE(); }
  }
  #undef STG_B
  #undef LD_A03
  #undef LD_A47

  // epilogue: p = exp(score/sqrtD + colbias); Z/W partials over this block's 256 cols
  const float invsq = 0.03608439182435161f;
  float vwv[4], cbl[4];
  #pragma unroll
  for (int nj = 0; nj < 4; ++nj){
    int r = l * R_ + n0 + wc * 64 + nj * 16 + ln;
    vwv[nj] = vw[r];
    cbl[nj] = cbg[r];
  }
  float* zr  = (float*)&Bs[0][0];   // [4][256]
  float* wrd = zr + 1024;           // [4][256]
  __syncthreads();                  // all b(11) reads done before Bs reuse
  #pragma unroll
  for (int mi = 0; mi < 8; ++mi){
    #pragma unroll
    for (int rg = 0; rg < 4; ++rg){
      float z = 0.f, w = 0.f;
      #pragma unroll
      for (int nj = 0; nj < 4; ++nj){
        float p = __expf(fmaf(acc[mi][nj][rg], invsq, cbl[nj]));
        z += p;
        w = fmaf(p, vwv[nj], w);
      }
      z += __shfl_xor(z, 1, 64); w += __shfl_xor(w, 1, 64);
      z += __shfl_xor(z, 2, 64); w += __shfl_xor(w, 2, 64);
      z += __shfl_xor(z, 4, 64); w += __shfl_xor(w, 4, 64);
      z += __shfl_xor(z, 8, 64); w += __shfl_xor(w, 8, 64);
      if (ln == 0){
        int row = wr * 128 + mi * 16 + lh * 4 + rg;
        zr[wc * 256 + row] = z;
        wrd[wc * 256 + row] = w;
      }
    }
  }
  __syncthreads();
  if (tid < 256){
    float z = zr[tid] + zr[256 + tid] + zr[512 + tid] + zr[768 + tid];
    float w = wrd[tid] + wrd[256 + tid] + wrd[512 + tid] + wrd[768 + tid];
    size_t o = (size_t)(l * 2 + nt) * 2048 + m0 + tid;
    Zp[o] = z;
    Wp[o] = w;
  }
}

// ---------------- K5b: combine N-halves -> d ----------------
__global__ __launch_bounds__(256) void k_reduce(const float* __restrict__ Zp, const float* __restrict__ Wp,
      const float* __restrict__ bdp, float* __restrict__ dws){
  int idx = blockIdx.x * 256 + threadIdx.x;
  float b = bdp[0];
  for (int i = idx; i < L_ * 2048; i += gridDim.x * 256){
    int l = i >> 11, g = i & 2047;
    int f = g >> 9, s = g & 511;
    float z = Zp[(size_t)(l * 2) * 2048 + g] + Zp[(size_t)(l * 2 + 1) * 2048 + g];
    float w = Wp[(size_t)(l * 2) * 2048 + g] + Wp[(size_t)(l * 2 + 1) * 2048 + g];
    dws[(size_t)(f * L_ + l) * S_ + s] = w / z + b;
  }
}

// ---------------- K5 fallback (ws too small for Ebf): reg-staged, linear Gb ----------------
__global__ __launch_bounds__(256) void k_attn_fb(const short* __restrict__ Gb, const float* __restrict__ E,
      const float* __restrict__ vw, const float* __restrict__ cbg,
      const float* __restrict__ bdp, float* __restrict__ dws){
  __shared__ __align__(16) short As[128 * 64];
  __shared__ __align__(16) short Bs[128 * 64];
  __shared__ float mM[2][128], mZ[2][128], mW[2][128];
  int b0 = blockIdx.x;
  int bid = (b0 & 7) * 206 + (b0 >> 3);
  int l  = bid >> 4;
  int f  = (bid >> 2) & 3;
  int sc = bid & 3;
  int s0 = sc * 128;
  int tid = threadIdx.x, lane = tid & 63, wid = tid >> 6;
  int wr = wid >> 1, wc = wid & 1, ln = lane & 15, lh = lane >> 4;
  const float invsq = 0.03608439182435161f;
  float sm_m[16], sm_z[16], sm_w[16];
  #pragma unroll
  for (int i = 0; i < 16; ++i){ sm_m[i] = -3.0e38f; sm_z[i] = 0.f; sm_w[i] = 0.f; }
  int srow = tid >> 1, hf = tid & 1;
  int swz = srow & 7;
  const short* gp = Gb + (size_t)(f * S_ + s0 + srow) * D_;
  for (int rt = 0; rt < 4; ++rt){
    f32x4 acc[4][4];
    #pragma unroll
    for (int i = 0; i < 4; ++i)
      #pragma unroll
      for (int j = 0; j < 4; ++j)
        acc[i][j] = (f32x4){0.f, 0.f, 0.f, 0.f};
    const float* ep = E + (size_t)(l * R_ + rt * 128 + srow) * D_;
    for (int k0 = 0; k0 < D_; k0 += 64){
      #pragma unroll
      for (int q = 0; q < 4; ++q){
        int k = hf * 32 + q * 8;
        short8 v = *reinterpret_cast<const short8*>(&gp[k0 + k]);
        *reinterpret_cast<short8*>(&As[srow * 64 + (((k >> 3) ^ swz) * 8)]) = v;
      }
      #pragma unroll
      for (int q = 0; q < 4; ++q){
        int k = hf * 32 + q * 8;
        float4 v0 = *reinterpret_cast<const float4*>(&ep[k0 + k]);
        float4 v1 = *reinterpret_cast<const float4*>(&ep[k0 + k + 4]);
        short8 p;
        p[0] = f2bf(v0.x); p[1] = f2bf(v0.y); p[2] = f2bf(v0.z); p[3] = f2bf(v0.w);
        p[4] = f2bf(v1.x); p[5] = f2bf(v1.y); p[6] = f2bf(v1.z); p[7] = f2bf(v1.w);
        *reinterpret_cast<short8*>(&Bs[srow * 64 + (((k >> 3) ^ swz) * 8)]) = p;
      }
      __syncthreads();
      mfma_tile(As, Bs, acc, wr, wc, ln, lh);
      __syncthreads();
    }
    float vwv[4], cbl[4];
    #pragma unroll
    for (int j = 0; j < 4; ++j){
      int r = l * R_ + rt * 128 + wc * 64 + j * 16 + ln;
      vwv[j] = vw[r];
      cbl[j] = cbg[r];
    }
    #pragma unroll
    for (int i = 0; i < 4; ++i){
      #pragma unroll
      for (int rg = 0; rg < 4; ++rg){
        float v0 = fmaf(acc[i][0][rg], invsq, cbl[0]);
        float v1 = fmaf(acc[i][1][rg], invsq, cbl[1]);
        float v2 = fmaf(acc[i][2][rg], invsq, cbl[2]);
        float v3 = fmaf(acc[i][3][rg], invsq, cbl[3]);
        float tm = fmaxf(fmaxf(v0, v1), fmaxf(v2, v3));
        int idx = i * 4 + rg;
        float mo = sm_m[idx];
        float nm = fmaxf(mo, tm);
        float scl = __expf(mo - nm);
        float p0 = __expf(v0 - nm), p1 = __expf(v1 - nm);
        float p2 = __expf(v2 - nm), p3 = __expf(v3 - nm);
        sm_z[idx] = fmaf(sm_z[idx], scl, (p0 + p1) + (p2 + p3));
        sm_w[idx] = fmaf(sm_w[idx], scl, fmaf(p0, vwv[0], fmaf(p1, vwv[1], fmaf(p2, vwv[2], p3 * vwv[3]))));
        sm_m[idx] = nm;
      }
    }
  }
  #pragma unroll
  for (int st = 1; st < 16; st <<= 1){
    #pragma unroll
    for (int idx = 0; idx < 16; ++idx){
      float om = __shfl_xor(sm_m[idx], st, 64);
      float oz = __shfl_xor(sm_z[idx], st, 64);
      float ow = __shfl_xor(sm_w[idx], st, 64);
      float nm = fmaxf(sm_m[idx], om);
      float e1 = __expf(sm_m[idx] - nm);
      float e2 = __expf(om - nm);
      sm_z[idx] = fmaf(sm_z[idx], e1, oz * e2);
      sm_w[idx] = fmaf(sm_w[idx], e1, ow * e2);
      sm_m[idx] = nm;
    }
  }
  if (ln == 0){
    #pragma unroll
    for (int i = 0; i < 4; ++i)
      #pragma unroll
      for (int rg = 0; rg < 4; ++rg){
        int row = wr * 64 + i * 16 + lh * 4 + rg;
        int idx = i * 4 + rg;
        mM[wc][row] = sm_m[idx]; mZ[wc][row] = sm_z[idx]; mW[wc][row] = sm_w[idx];
      }
  }
  __syncthreads();
  if (tid < 128){
    float ma = mM[0][tid], mb = mM[1][tid];
    float nm = fmaxf(ma, mb);
    float ea = __expf(ma - nm), eb = __expf(mb - nm);
    float z = mZ[0][tid] * ea + mZ[1][tid] * eb;
    float w = mW[0][tid] * ea + mW[1][tid] * eb;
    dws[(size_t)(f * L_ + l) * S_ + s0 + tid] = w / z + bdp[0];
  }
}

// ---------------- K6: law, accu, term ----------------
__global__ __launch_bounds__(256) void k_final(const float* __restrict__ dws, const float* __restrict__ wlp,
      const float* __restrict__ blp, const float* __restrict__ Wa, const float* __restrict__ ba,
      const float* __restrict__ Wt, const float* __restrict__ bt, float* __restrict__ out){
  int f = blockIdx.x, tid = threadIdx.x;
  __shared__ float lawf[L_];
  if (tid < L_){
    const float* dp = dws + (size_t)(f * L_ + tid) * S_;
    float s = 0.f;
    #pragma unroll 4
    for (int i = 0; i < S_; i += 4){
      float4 v  = *reinterpret_cast<const float4*>(&dp[i]);
      float4 wv = *reinterpret_cast<const float4*>(&wlp[i]);
      s = fmaf(v.x, wv.x, fmaf(v.y, wv.y, fmaf(v.z, wv.z, fmaf(v.w, wv.w, s))));
    }
    s += blp[0];
    out[f * L_ + tid] = s;
    lawf[tid] = s;
  }
  __syncthreads();
  if (tid < NACCU){
    float s = ba[tid];
    for (int ll = 0; ll < L_; ++ll) s = fmaf(lawf[ll], Wa[tid * L_ + ll], s);
    out[F_ * L_ + f * NACCU + tid] = s;
  }
  if (tid >= 128 && tid < 128 + NTERM){
    int t = tid - 128;
    float s = bt[t];
    for (int ll = 0; ll < L_; ++ll) s = fmaf(lawf[ll], Wt[t * L_ + ll], s);
    out[F_ * L_ + F_ * NACCU + f * NTERM + t] = s;
  }
}

extern "C" void kernel_launch(void* const* d_in, const int* in_sizes, int n_in,
                              void* d_out, int out_size, void* d_ws, size_t ws_size,
                              hipStream_t stream){
  (void)in_sizes; (void)n_in; (void)out_size;
  const float* fact = (const float*)d_in[0];
  const float* E    = (const float*)d_in[1];
  const float* Wq   = (const float*)d_in[2];
  const float* bq   = (const float*)d_in[3];
  const float* Wk   = (const float*)d_in[4];
  const float* bk   = (const float*)d_in[5];
  const float* Wv   = (const float*)d_in[6];
  const float* bv   = (const float*)d_in[7];
  const float* wd   = (const float*)d_in[8];
  const float* bdp  = (const float*)d_in[9];
  const float* wlp  = (const float*)d_in[10];
  const float* blp  = (const float*)d_in[11];
  const float* Wa   = (const float*)d_in[12];
  const float* ba   = (const float*)d_in[13];
  const float* Wt   = (const float*)d_in[14];
  const float* bt   = (const float*)d_in[15];
  const float* mask = (const float*)d_in[16];
  (void)bk;
  char* ws = (char*)d_ws;
  float* u   = (float*)(ws + 0);
  float* v2  = (float*)(ws + 3072);
  float* cw  = (float*)(ws + 6144);
  short* Mt  = (short*)(ws + 6400);
  short* Gb  = (short*)(ws + 1186048);
  float* vw  = (float*)(ws + 4331776);
  float* cb  = (float*)(ws + 4542720);
  float* dws = (float*)(ws + 4753664);
  short* Ebf = (short*)(ws + 5597440);
  float* Zp  = (float*)(ws + 86599936);
  float* Wp  = (float*)(ws + 88287488);
  const size_t need2 = 89975040ULL;
  bool pre = ws_size >= need2;
  float* out = (float*)d_out;

  k_prep<<<dim3(4), dim3(256), 0, stream>>>(Wv, wd, Wk, bq, bv, u, v2, cw);
  k_gemm_M<<<dim3(36), dim3(256), 0, stream>>>(Wk, Wq, Mt);
  k_gemm_G<<<dim3(96), dim3(256), 0, stream>>>(fact, Mt, Gb);
  k_lawprep<<<dim3(824), dim3(256), 0, stream>>>(E, u, v2, cw, mask, vw, cb, pre ? Ebf : (short*)nullptr);
  if (pre){
    k_attn8<<<dim3(1648), dim3(512), 0, stream>>>(Gb, Ebf, vw, cb, Zp, Wp);
    k_reduce<<<dim3(824), dim3(256), 0, stream>>>(Zp, Wp, bdp, dws);
  } else {
    k_attn_fb<<<dim3(1648), dim3(256), 0, stream>>>(Gb, E, vw, cb, bdp, dws);
  }
  k_final<<<dim3(4), dim3(256), 0, stream>>>(dws, wlp, blp, Wa, ba, Wt, bt, out);
}

// Round 8
// 393.348 us; speedup vs baseline: 1.5754x; 1.5754x over previous
//
#include <hip/hip_runtime.h>

#define D_ 768
#define S_ 512
#define R_ 512
#define L_ 103
#define F_ 4
#define NACCU 119
#define NTERM 11

using short8  = __attribute__((ext_vector_type(8))) short;
using short4v = __attribute__((ext_vector_type(4))) short;
using f32x4   = __attribute__((ext_vector_type(4))) float;

__device__ __forceinline__ short f2bf(float x){
  unsigned u = __float_as_uint(x);
  unsigned r = (u + 0x7FFFu + ((u >> 16) & 1u)) >> 16;  // RNE
  return (short)r;
}

// async global->LDS, 16B per lane (global_load_lds_dwordx4)
__device__ __forceinline__ void gload16(const short* g, short* l){
  __builtin_amdgcn_global_load_lds(
      (const __attribute__((address_space(1))) void*)g,
      (__attribute__((address_space(3))) void*)l, 16, 0, 0);
}

#define SFENCE() __builtin_amdgcn_sched_barrier(0)
#define BAR()    __builtin_amdgcn_s_barrier()

// ---------------- K1: u = Wv^T w_dprob, v2 = Wk^T bq, c = bv.w_dprob ----------------
__global__ void k_prep(const float* __restrict__ Wv, const float* __restrict__ wd,
                       const float* __restrict__ Wk, const float* __restrict__ bq,
                       const float* __restrict__ bv,
                       float* __restrict__ u, float* __restrict__ v2, float* __restrict__ cw){
  int tid = threadIdx.x;
  if (blockIdx.x < 3){
    int d = blockIdx.x * 256 + tid;
    float su = 0.f, sv = 0.f;
    #pragma unroll 8
    for (int e = 0; e < D_; ++e){
      su = fmaf(Wv[e * D_ + d], wd[e], su);
      sv = fmaf(Wk[e * D_ + d], bq[e], sv);
    }
    u[d] = su; v2[d] = sv;
  } else {
    __shared__ float red[256];
    float p = bv[tid] * wd[tid] + bv[tid + 256] * wd[tid + 256] + bv[tid + 512] * wd[tid + 512];
    red[tid] = p;
    __syncthreads();
    for (int s = 128; s > 0; s >>= 1){
      if (tid < s) red[tid] += red[tid + s];
      __syncthreads();
    }
    if (tid == 0) cw[0] = red[0];
  }
}

// Shared MFMA inner step (used by fallback + small GEMMs)
__device__ __forceinline__ void mfma_tile(const short* As, const short* Bs, f32x4 (&acc)[4][4],
                                          int wr, int wc, int ln, int lh){
  #pragma unroll
  for (int half = 0; half < 2; ++half){
    short8 a[4], b[4];
    #pragma unroll
    for (int i = 0; i < 4; ++i){
      int row = wr * 64 + i * 16 + ln;
      int ch = (lh + half * 4) ^ (row & 7);
      a[i] = *reinterpret_cast<const short8*>(&As[row * 64 + ch * 8]);
    }
    #pragma unroll
    for (int j = 0; j < 4; ++j){
      int row = wc * 64 + j * 16 + ln;
      int ch = (lh + half * 4) ^ (row & 7);
      b[j] = *reinterpret_cast<const short8*>(&Bs[row * 64 + ch * 8]);
    }
    #pragma unroll
    for (int i = 0; i < 4; ++i)
      #pragma unroll
      for (int j = 0; j < 4; ++j)
        acc[i][j] = __builtin_amdgcn_mfma_f32_16x16x32_bf16(a[i], b[j], acc[i][j], 0, 0, 0);
  }
}

// ---------------- K2: Mt[d',d] = sum_e Wk[e,d'] * Wq[e,d]  (bf16 out, linear) ----------------
__global__ __launch_bounds__(256) void k_gemm_M(const float* __restrict__ Wk, const float* __restrict__ Wq,
                                                short* __restrict__ Mt){
  __shared__ __align__(16) short As[128 * 64];
  __shared__ __align__(16) short Bs[128 * 64];
  int bid = blockIdx.x;
  int m0 = (bid / 6) * 128, n0 = (bid % 6) * 128;
  int tid = threadIdx.x, lane = tid & 63, wid = tid >> 6;
  int wr = wid >> 1, wc = wid & 1, ln = lane & 15, lh = lane >> 4;
  f32x4 acc[4][4];
  #pragma unroll
  for (int i = 0; i < 4; ++i)
    #pragma unroll
    for (int j = 0; j < 4; ++j)
      acc[i][j] = (f32x4){0.f, 0.f, 0.f, 0.f};
  int mm = (tid & 31) * 4;
  int kb = tid >> 5;   // 0..7
  for (int k0 = 0; k0 < D_; k0 += 64){
    #pragma unroll
    for (int ki = 0; ki < 8; ++ki){
      int k = kb + ki * 8;
      float4 va = *reinterpret_cast<const float4*>(&Wk[(k0 + k) * D_ + m0 + mm]);
      float4 vb = *reinterpret_cast<const float4*>(&Wq[(k0 + k) * D_ + n0 + mm]);
      As[(mm + 0) * 64 + ((ki ^ ((mm + 0) & 7)) * 8) + kb] = f2bf(va.x);
      As[(mm + 1) * 64 + ((ki ^ ((mm + 1) & 7)) * 8) + kb] = f2bf(va.y);
      As[(mm + 2) * 64 + ((ki ^ ((mm + 2) & 7)) * 8) + kb] = f2bf(va.z);
      As[(mm + 3) * 64 + ((ki ^ ((mm + 3) & 7)) * 8) + kb] = f2bf(va.w);
      Bs[(mm + 0) * 64 + ((ki ^ ((mm + 0) & 7)) * 8) + kb] = f2bf(vb.x);
      Bs[(mm + 1) * 64 + ((ki ^ ((mm + 1) & 7)) * 8) + kb] = f2bf(vb.y);
      Bs[(mm + 2) * 64 + ((ki ^ ((mm + 2) & 7)) * 8) + kb] = f2bf(vb.z);
      Bs[(mm + 3) * 64 + ((ki ^ ((mm + 3) & 7)) * 8) + kb] = f2bf(vb.w);
    }
    __syncthreads();
    mfma_tile(As, Bs, acc, wr, wc, ln, lh);
    __syncthreads();
  }
  #pragma unroll
  for (int i = 0; i < 4; ++i)
    #pragma unroll
    for (int j = 0; j < 4; ++j)
      #pragma unroll
      for (int rg = 0; rg < 4; ++rg){
        int row = m0 + wr * 64 + i * 16 + lh * 4 + rg;
        int col = n0 + wc * 64 + j * 16 + ln;
        Mt[row * D_ + col] = f2bf(acc[i][j][rg]);
      }
}

// ---------------- K3: G[t,d'] = sum_d fact[t,d] * Mt[d',d]  (bf16 out, PRE-SWIZZLED) ----------------
__global__ __launch_bounds__(256) void k_gemm_G(const float* __restrict__ A, const short* __restrict__ Mt,
                                                short* __restrict__ Gb){
  __shared__ __align__(16) short As[128 * 64];
  __shared__ __align__(16) short Bs[128 * 64];
  int bid = blockIdx.x;
  int m0 = (bid / 6) * 128, n0 = (bid % 6) * 128;
  int tid = threadIdx.x, lane = tid & 63, wid = tid >> 6;
  int wr = wid >> 1, wc = wid & 1, ln = lane & 15, lh = lane >> 4;
  f32x4 acc[4][4];
  #pragma unroll
  for (int i = 0; i < 4; ++i)
    #pragma unroll
    for (int j = 0; j < 4; ++j)
      acc[i][j] = (f32x4){0.f, 0.f, 0.f, 0.f};
  int srow = tid >> 1, hf = tid & 1;
  int swz = srow & 7;
  const float* ap = A  + (size_t)(m0 + srow) * D_;
  const short* bp = Mt + (size_t)(n0 + srow) * D_;
  for (int k0 = 0; k0 < D_; k0 += 64){
    #pragma unroll
    for (int q = 0; q < 8; ++q){
      int k = hf * 32 + q * 4;
      float4 v = *reinterpret_cast<const float4*>(&ap[k0 + k]);
      short4v p; p[0] = f2bf(v.x); p[1] = f2bf(v.y); p[2] = f2bf(v.z); p[3] = f2bf(v.w);
      *reinterpret_cast<short4v*>(&As[srow * 64 + (((k >> 3) ^ swz) * 8) + (k & 7)]) = p;
    }
    #pragma unroll
    for (int q = 0; q < 4; ++q){
      int k = hf * 32 + q * 8;
      short8 v = *reinterpret_cast<const short8*>(&bp[k0 + k]);
      *reinterpret_cast<short8*>(&Bs[srow * 64 + (((k >> 3) ^ swz) * 8)]) = v;
    }
    __syncthreads();
    mfma_tile(As, Bs, acc, wr, wc, ln, lh);
    __syncthreads();
  }
  // store pre-swizzled: Gb[row][chi, mid ^ (row&7), lo] = value at (row, col)
  #pragma unroll
  for (int i = 0; i < 4; ++i)
    #pragma unroll
    for (int j = 0; j < 4; ++j)
      #pragma unroll
      for (int rg = 0; rg < 4; ++rg){
        int row = m0 + wr * 64 + i * 16 + lh * 4 + rg;
        int col = n0 + wc * 64 + j * 16 + ln;
        int chi = col >> 6, mid = (col >> 3) & 7, lo = col & 7;
        Gb[row * D_ + chi * 64 + ((mid ^ (row & 7)) << 3) + lo] = f2bf(acc[i][j][rg]);
      }
}

// ---------------- K4: vw[l,r], colbias[l,r]; E->bf16 PRE-SWIZZLED (2-row ILP) ----------------
__global__ __launch_bounds__(256) void k_lawprep(const float* __restrict__ E, const float* __restrict__ u,
      const float* __restrict__ v2, const float* __restrict__ cw, const float* __restrict__ mask,
      float* __restrict__ vw, float* __restrict__ cb, short* __restrict__ ebf){
  int lane = threadIdx.x & 63;
  int w  = (blockIdx.x * blockDim.x + threadIdx.x) >> 6;
  int nw = (gridDim.x * blockDim.x) >> 6;
  float uu[12], vv[12];
  #pragma unroll
  for (int i = 0; i < 3; ++i){
    float4 a = *reinterpret_cast<const float4*>(&u[i * 256 + lane * 4]);
    float4 b = *reinterpret_cast<const float4*>(&v2[i * 256 + lane * 4]);
    uu[i*4+0] = a.x; uu[i*4+1] = a.y; uu[i*4+2] = a.z; uu[i*4+3] = a.w;
    vv[i*4+0] = b.x; vv[i*4+1] = b.y; vv[i*4+2] = b.z; vv[i*4+3] = b.w;
  }
  float c = cw[0];
  const float invsq = 0.03608439182435161f;
  int mid = (lane >> 1) & 7;
  int lo  = (lane & 1) * 4;
  int chiB = lane >> 4;
  for (int row = w * 2; row < L_ * R_; row += nw * 2){
    const float* e0 = E + (size_t)row * D_;
    const float* e1 = e0 + D_;
    int rs0 = row & 7, rs1 = (row + 1) & 7;
    float s1a = 0.f, s2a = 0.f, s1b = 0.f, s2b = 0.f;
    #pragma unroll
    for (int i = 0; i < 3; ++i){
      float4 ev0 = *reinterpret_cast<const float4*>(&e0[i * 256 + lane * 4]);
      float4 ev1 = *reinterpret_cast<const float4*>(&e1[i * 256 + lane * 4]);
      s1a = fmaf(ev0.x, uu[i*4+0], fmaf(ev0.y, uu[i*4+1], fmaf(ev0.z, uu[i*4+2], fmaf(ev0.w, uu[i*4+3], s1a))));
      s2a = fmaf(ev0.x, vv[i*4+0], fmaf(ev0.y, vv[i*4+1], fmaf(ev0.z, vv[i*4+2], fmaf(ev0.w, vv[i*4+3], s2a))));
      s1b = fmaf(ev1.x, uu[i*4+0], fmaf(ev1.y, uu[i*4+1], fmaf(ev1.z, uu[i*4+2], fmaf(ev1.w, uu[i*4+3], s1b))));
      s2b = fmaf(ev1.x, vv[i*4+0], fmaf(ev1.y, vv[i*4+1], fmaf(ev1.z, vv[i*4+2], fmaf(ev1.w, vv[i*4+3], s2b))));
      if (ebf){
        short4v p0, p1;
        p0[0] = f2bf(ev0.x); p0[1] = f2bf(ev0.y); p0[2] = f2bf(ev0.z); p0[3] = f2bf(ev0.w);
        p1[0] = f2bf(ev1.x); p1[1] = f2bf(ev1.y); p1[2] = f2bf(ev1.z); p1[3] = f2bf(ev1.w);
        int chi = i * 4 + chiB;
        *reinterpret_cast<short4v*>(&ebf[(size_t)row * D_ + chi * 64 + ((mid ^ rs0) << 3) + lo]) = p0;
        *reinterpret_cast<short4v*>(&ebf[(size_t)(row + 1) * D_ + chi * 64 + ((mid ^ rs1) << 3) + lo]) = p1;
      }
    }
    #pragma unroll
    for (int st = 1; st < 64; st <<= 1){
      s1a += __shfl_xor(s1a, st, 64);
      s2a += __shfl_xor(s2a, st, 64);
      s1b += __shfl_xor(s1b, st, 64);
      s2b += __shfl_xor(s2b, st, 64);
    }
    if (lane == 0){
      vw[row] = s1a + c;
      cb[row] = fmaf(s2a, invsq, mask[row]);
      vw[row + 1] = s1b + c;
      cb[row + 1] = fmaf(s2b, invsq, mask[row + 1]);
    }
  }
}

// -------- helpers for the 1-barrier kernel --------
__device__ __forceinline__ void rd4f(const short* base, int rowBase, int ln, int lh, short8 (&d)[2][4]){
  #pragma unroll
  for (int ks = 0; ks < 2; ++ks)
    #pragma unroll
    for (int i = 0; i < 4; ++i){
      int row = rowBase + i * 16 + ln;
      int ch = (ks * 4 + lh) ^ (row & 7);
      d[ks][i] = *reinterpret_cast<const short8*>(&base[row * 64 + ch * 8]);
    }
}
__device__ __forceinline__ void rd2f(const short* base, int rowBase, int ln, int lh, short8 (&d)[2][2]){
  #pragma unroll
  for (int ks = 0; ks < 2; ++ks)
    #pragma unroll
    for (int j = 0; j < 2; ++j){
      int row = rowBase + j * 16 + ln;
      int ch = (ks * 4 + lh) ^ (row & 7);
      d[ks][j] = *reinterpret_cast<const short8*>(&base[row * 64 + ch * 8]);
    }
}
__device__ __forceinline__ void mm42(const short8 (&a)[2][4], const short8 (&b)[2][2],
                                     f32x4 (&acc)[8][4], int mo, int no){
  __builtin_amdgcn_s_setprio(1);
  #pragma unroll
  for (int ks = 0; ks < 2; ++ks)
    #pragma unroll
    for (int i = 0; i < 4; ++i)
      #pragma unroll
      for (int j = 0; j < 2; ++j)
        acc[mo + i][no + j] = __builtin_amdgcn_mfma_f32_16x16x32_bf16(a[ks][i], b[ks][j], acc[mo + i][no + j], 0, 0, 0);
  __builtin_amdgcn_s_setprio(0);
}

// ---------------- K5 v4: 1 barrier/K-tile, zero intra-tile fences ----------------
// Per tile t: issue STG(t+1) into buf[(t+1)&1]; then 24 ds_reads + 64 MFMAs of buf[t&1]
// with NO barriers/fences between - compiler's fine-grained lgkmcnt lets wave-skewed
// reads hide under other waves' MFMAs. Tile-end: vmcnt(0) (drains tile-old STG, cheap)
// + s_barrier. Hazards: STG(t+1) writes opposite parity of the read buffer (disjoint);
// barrier(t) retires all reads of buf[t&1] before STG(t+2) overwrites it; SFENCE after
// BAR stops next-tile read hoisting. A stays in LDS (Gb pre-swizzled); non-acc VGPR
// stays ~128 so acc's 128 AGPRs fit the unified file at 2 waves/SIMD (R7 spill lesson).
__global__ __launch_bounds__(512, 2) void k_attn8(const short* __restrict__ Gb,
      const short* __restrict__ Ebf, const float* __restrict__ vw, const float* __restrict__ cbg,
      float* __restrict__ Zp, float* __restrict__ Wp){
  __shared__ __align__(16) short As[2][16384];
  __shared__ __align__(16) short Bs[2][16384];
  int b0 = blockIdx.x;
  int bid = (b0 & 7) * 206 + (b0 >> 3);     // 1648 = 8*206, bijective
  int l  = bid >> 4;
  int mt = (bid >> 1) & 7;
  int nt = bid & 1;
  int m0 = mt * 256, n0 = nt * 256;
  int tid = threadIdx.x, lane = tid & 63, wid = tid >> 6;
  int wr = wid >> 2, wc = wid & 3, ln = lane & 15, lh = lane >> 4;
  int c0 = tid, c1 = tid + 512;
  const short* gA0 = Gb  + (size_t)(m0 + (c0 >> 3)) * D_ + (c0 & 7) * 8;
  const short* gA1 = Gb  + (size_t)(m0 + (c1 >> 3)) * D_ + (c1 & 7) * 8;
  const short* gB0 = Ebf + (size_t)(l * R_ + n0 + (c0 >> 3)) * D_ + (c0 & 7) * 8;
  const short* gB1 = Ebf + (size_t)(l * R_ + n0 + (c1 >> 3)) * D_ + (c1 & 7) * 8;

  f32x4 acc[8][4];
  #pragma unroll
  for (int i = 0; i < 8; ++i)
    #pragma unroll
    for (int j = 0; j < 4; ++j)
      acc[i][j] = (f32x4){0.f, 0.f, 0.f, 0.f};

  #define STG_AB(t) { \
    short* da_ = &As[(t) & 1][0]; short* db_ = &Bs[(t) & 1][0]; \
    gload16(gA0 + (t) * 64, da_ + c0 * 8); \
    gload16(gA1 + (t) * 64, da_ + c1 * 8); \
    gload16(gA0 + (size_t)128 * D_ + (t) * 64, da_ + 8192 + c0 * 8); \
    gload16(gA1 + (size_t)128 * D_ + (t) * 64, da_ + 8192 + c1 * 8); \
    gload16(gB0 + (t) * 64, db_ + c0 * 8); \
    gload16(gB1 + (t) * 64, db_ + c1 * 8); \
    gload16(gB0 + (size_t)128 * D_ + (t) * 64, db_ + 8192 + c0 * 8); \
    gload16(gB1 + (size_t)128 * D_ + (t) * 64, db_ + 8192 + c1 * 8); }

  // prologue: tile 0 staged, drained, visible
  STG_AB(0);
  asm volatile("s_waitcnt vmcnt(0)" ::: "memory");
  BAR(); SFENCE();

  #pragma unroll 2
  for (int t = 0; t < 12; ++t){
    if (t + 1 < 12) STG_AB(t + 1);
    SFENCE();   // pin STG issue before the compute region (issue-early)
    const short* Asl = As[t & 1];
    const short* Bsl = Bs[t & 1];
    short8 a03[2][4], a47[2][4], b01[2][2], b23[2][2];
    rd4f(Asl, wr * 128, ln, lh, a03);
    rd2f(Bsl, wc * 64, ln, lh, b01);
    mm42(a03, b01, acc, 0, 0);
    rd4f(Asl, wr * 128 + 64, ln, lh, a47);
    mm42(a47, b01, acc, 4, 0);
    rd2f(Bsl, wc * 64 + 32, ln, lh, b23);
    mm42(a47, b23, acc, 4, 2);
    mm42(a03, b23, acc, 0, 2);
    // tile-old STG retired (issued ~2500 cyc ago) -> cheap drain; then block-wide flip
    asm volatile("s_waitcnt vmcnt(0)" ::: "memory");
    BAR(); SFENCE();
  }
  #undef STG_AB

  // epilogue: p = exp(score/sqrtD + colbias); Z/W partials over this block's 256 cols
  const float invsq = 0.03608439182435161f;
  float vwv[4], cbl[4];
  #pragma unroll
  for (int nj = 0; nj < 4; ++nj){
    int r = l * R_ + n0 + wc * 64 + nj * 16 + ln;
    vwv[nj] = vw[r];
    cbl[nj] = cbg[r];
  }
  float* zr  = (float*)&As[0][0];   // [4][256]
  float* wrd = zr + 1024;           // [4][256]
  #pragma unroll
  for (int mi = 0; mi < 8; ++mi){
    #pragma unroll
    for (int rg = 0; rg < 4; ++rg){
      float z = 0.f, w = 0.f;
      #pragma unroll
      for (int nj = 0; nj < 4; ++nj){
        float p = __expf(fmaf(acc[mi][nj][rg], invsq, cbl[nj]));
        z += p;
        w = fmaf(p, vwv[nj], w);
      }
      z += __shfl_xor(z, 1, 64); w += __shfl_xor(w, 1, 64);
      z += __shfl_xor(z, 2, 64); w += __shfl_xor(w, 2, 64);
      z += __shfl_xor(z, 4, 64); w += __shfl_xor(w, 4, 64);
      z += __shfl_xor(z, 8, 64); w += __shfl_xor(w, 8, 64);
      if (ln == 0){
        int row = wr * 128 + mi * 16 + lh * 4 + rg;
        zr[wc * 256 + row] = z;
        wrd[wc * 256 + row] = w;
      }
    }
  }
  __syncthreads();
  if (tid < 256){
    float z = zr[tid] + zr[256 + tid] + zr[512 + tid] + zr[768 + tid];
    float w = wrd[tid] + wrd[256 + tid] + wrd[512 + tid] + wrd[768 + tid];
    size_t o = (size_t)(l * 2 + nt) * 2048 + m0 + tid;
    Zp[o] = z;
    Wp[o] = w;
  }
}

// ---------------- K5b: combine N-halves -> d ----------------
__global__ __launch_bounds__(256) void k_reduce(const float* __restrict__ Zp, const float* __restrict__ Wp,
      const float* __restrict__ bdp, float* __restrict__ dws){
  int idx = blockIdx.x * 256 + threadIdx.x;
  float b = bdp[0];
  for (int i = idx; i < L_ * 2048; i += gridDim.x * 256){
    int l = i >> 11, g = i & 2047;
    int f = g >> 9, s = g & 511;
    float z = Zp[(size_t)(l * 2) * 2048 + g] + Zp[(size_t)(l * 2 + 1) * 2048 + g];
    float w = Wp[(size_t)(l * 2) * 2048 + g] + Wp[(size_t)(l * 2 + 1) * 2048 + g];
    dws[(size_t)(f * L_ + l) * S_ + s] = w / z + b;
  }
}

// ---------------- K5 fallback (ws too small for Ebf): R2-validated path ----------------
__global__ __launch_bounds__(256) void k_attn_fb(const short* __restrict__ Gb, const float* __restrict__ E,
      const float* __restrict__ vw, const float* __restrict__ cbg,
      const float* __restrict__ bdp, float* __restrict__ dws){
  __shared__ __align__(16) short As[128 * 64];
  __shared__ __align__(16) short Bs[128 * 64];
  __shared__ float mM[2][128], mZ[2][128], mW[2][128];
  int b0 = blockIdx.x;
  int bid = (b0 & 7) * 206 + (b0 >> 3);
  int l  = bid >> 4;
  int f  = (bid >> 2) & 3;
  int sc = bid & 3;
  int s0 = sc * 128;
  int tid = threadIdx.x, lane = tid & 63, wid = tid >> 6;
  int wr = wid >> 1, wc = wid & 1, ln = lane & 15, lh = lane >> 4;
  const float invsq = 0.03608439182435161f;
  float sm_m[16], sm_z[16], sm_w[16];
  #pragma unroll
  for (int i = 0; i < 16; ++i){ sm_m[i] = -3.0e38f; sm_z[i] = 0.f; sm_w[i] = 0.f; }
  int lrow = (lane >> 3), lch = lane & 7;
  const short* gaBase = Gb + ((size_t)(f * S_ + s0 + wid * 32 + lrow) * D_ + lch * 8);
  short* ldsA = As + wid * 32 * 64;
  int srow = tid >> 1, hf = tid & 1;
  int swz = srow & 7;
  for (int rt = 0; rt < 4; ++rt){
    f32x4 acc[4][4];
    #pragma unroll
    for (int i = 0; i < 4; ++i)
      #pragma unroll
      for (int j = 0; j < 4; ++j)
        acc[i][j] = (f32x4){0.f, 0.f, 0.f, 0.f};
    const float* ep = E + (size_t)(l * R_ + rt * 128 + srow) * D_;
    for (int k0 = 0; k0 < D_; k0 += 64){
      #pragma unroll
      for (int q = 0; q < 4; ++q)
        gload16(gaBase + (size_t)q * 8 * D_ + k0, ldsA + q * 512);
      #pragma unroll
      for (int q = 0; q < 4; ++q){
        int k = hf * 32 + q * 8;
        float4 v0 = *reinterpret_cast<const float4*>(&ep[k0 + k]);
        float4 v1 = *reinterpret_cast<const float4*>(&ep[k0 + k + 4]);
        short8 p;
        p[0] = f2bf(v0.x); p[1] = f2bf(v0.y); p[2] = f2bf(v0.z); p[3] = f2bf(v0.w);
        p[4] = f2bf(v1.x); p[5] = f2bf(v1.y); p[6] = f2bf(v1.z); p[7] = f2bf(v1.w);
        *reinterpret_cast<short8*>(&Bs[srow * 64 + (((k >> 3) ^ swz) * 8)]) = p;
      }
      __syncthreads();
      mfma_tile(As, Bs, acc, wr, wc, ln, lh);
      __syncthreads();
    }
    float vwv[4], cbl[4];
    #pragma unroll
    for (int j = 0; j < 4; ++j){
      int r = l * R_ + rt * 128 + wc * 64 + j * 16 + ln;
      vwv[j] = vw[r];
      cbl[j] = cbg[r];
    }
    #pragma unroll
    for (int i = 0; i < 4; ++i){
      #pragma unroll
      for (int rg = 0; rg < 4; ++rg){
        float v0 = fmaf(acc[i][0][rg], invsq, cbl[0]);
        float v1 = fmaf(acc[i][1][rg], invsq, cbl[1]);
        float v2 = fmaf(acc[i][2][rg], invsq, cbl[2]);
        float v3 = fmaf(acc[i][3][rg], invsq, cbl[3]);
        float tm = fmaxf(fmaxf(v0, v1), fmaxf(v2, v3));
        int idx = i * 4 + rg;
        float mo = sm_m[idx];
        float nm = fmaxf(mo, tm);
        float scl = __expf(mo - nm);
        float p0 = __expf(v0 - nm), p1 = __expf(v1 - nm);
        float p2 = __expf(v2 - nm), p3 = __expf(v3 - nm);
        sm_z[idx] = fmaf(sm_z[idx], scl, (p0 + p1) + (p2 + p3));
        sm_w[idx] = fmaf(sm_w[idx], scl, fmaf(p0, vwv[0], fmaf(p1, vwv[1], fmaf(p2, vwv[2], p3 * vwv[3]))));
        sm_m[idx] = nm;
      }
    }
  }
  #pragma unroll
  for (int st = 1; st < 16; st <<= 1){
    #pragma unroll
    for (int idx = 0; idx < 16; ++idx){
      float om = __shfl_xor(sm_m[idx], st, 64);
      float oz = __shfl_xor(sm_z[idx], st, 64);
      float ow = __shfl_xor(sm_w[idx], st, 64);
      float nm = fmaxf(sm_m[idx], om);
      float e1 = __expf(sm_m[idx] - nm);
      float e2 = __expf(om - nm);
      sm_z[idx] = fmaf(sm_z[idx], e1, oz * e2);
      sm_w[idx] = fmaf(sm_w[idx], e1, ow * e2);
      sm_m[idx] = nm;
    }
  }
  if (ln == 0){
    #pragma unroll
    for (int i = 0; i < 4; ++i)
      #pragma unroll
      for (int rg = 0; rg < 4; ++rg){
        int row = wr * 64 + i * 16 + lh * 4 + rg;
        int idx = i * 4 + rg;
        mM[wc][row] = sm_m[idx]; mZ[wc][row] = sm_z[idx]; mW[wc][row] = sm_w[idx];
      }
  }
  __syncthreads();
  if (tid < 128){
    float ma = mM[0][tid], mb = mM[1][tid];
    float nm = fmaxf(ma, mb);
    float ea = __expf(ma - nm), eb = __expf(mb - nm);
    float z = mZ[0][tid] * ea + mZ[1][tid] * eb;
    float w = mW[0][tid] * ea + mW[1][tid] * eb;
    dws[(size_t)(f * L_ + l) * S_ + s0 + tid] = w / z + bdp[0];
  }
}

// ---------------- K6: law, accu, term ----------------
__global__ __launch_bounds__(256) void k_final(const float* __restrict__ dws, const float* __restrict__ wlp,
      const float* __restrict__ blp, const float* __restrict__ Wa, const float* __restrict__ ba,
      const float* __restrict__ Wt, const float* __restrict__ bt, float* __restrict__ out){
  int f = blockIdx.x, tid = threadIdx.x;
  __shared__ float lawf[L_];
  if (tid < L_){
    const float* dp = dws + (size_t)(f * L_ + tid) * S_;
    float s = 0.f;
    #pragma unroll 4
    for (int i = 0; i < S_; i += 4){
      float4 v  = *reinterpret_cast<const float4*>(&dp[i]);
      float4 wv = *reinterpret_cast<const float4*>(&wlp[i]);
      s = fmaf(v.x, wv.x, fmaf(v.y, wv.y, fmaf(v.z, wv.z, fmaf(v.w, wv.w, s))));
    }
    s += blp[0];
    out[f * L_ + tid] = s;
    lawf[tid] = s;
  }
  __syncthreads();
  if (tid < NACCU){
    float s = ba[tid];
    for (int ll = 0; ll < L_; ++ll) s = fmaf(lawf[ll], Wa[tid * L_ + ll], s);
    out[F_ * L_ + f * NACCU + tid] = s;
  }
  if (tid >= 128 && tid < 128 + NTERM){
    int t = tid - 128;
    float s = bt[t];
    for (int ll = 0; ll < L_; ++ll) s = fmaf(lawf[ll], Wt[t * L_ + ll], s);
    out[F_ * L_ + F_ * NACCU + f * NTERM + t] = s;
  }
}

extern "C" void kernel_launch(void* const* d_in, const int* in_sizes, int n_in,
                              void* d_out, int out_size, void* d_ws, size_t ws_size,
                              hipStream_t stream){
  (void)in_sizes; (void)n_in; (void)out_size;
  const float* fact = (const float*)d_in[0];
  const float* E    = (const float*)d_in[1];
  const float* Wq   = (const float*)d_in[2];
  const float* bq   = (const float*)d_in[3];
  const float* Wk   = (const float*)d_in[4];
  const float* bk   = (const float*)d_in[5];
  const float* Wv   = (const float*)d_in[6];
  const float* bv   = (const float*)d_in[7];
  const float* wd   = (const float*)d_in[8];
  const float* bdp  = (const float*)d_in[9];
  const float* wlp  = (const float*)d_in[10];
  const float* blp  = (const float*)d_in[11];
  const float* Wa   = (const float*)d_in[12];
  const float* ba   = (const float*)d_in[13];
  const float* Wt   = (const float*)d_in[14];
  const float* bt   = (const float*)d_in[15];
  const float* mask = (const float*)d_in[16];
  (void)bk;
  char* ws = (char*)d_ws;
  float* u   = (float*)(ws + 0);
  float* v2  = (float*)(ws + 3072);
  float* cw  = (float*)(ws + 6144);
  short* Mt  = (short*)(ws + 6400);
  short* Gb  = (short*)(ws + 1186048);
  float* vw  = (float*)(ws + 4331776);
  float* cb  = (float*)(ws + 4542720);
  float* dws = (float*)(ws + 4753664);
  short* Ebf = (short*)(ws + 5597440);
  float* Zp  = (float*)(ws + 86599936);
  float* Wp  = (float*)(ws + 88287488);
  const size_t need2 = 89975040ULL;
  bool pre = ws_size >= need2;
  float* out = (float*)d_out;

  k_prep<<<dim3(4), dim3(256), 0, stream>>>(Wv, wd, Wk, bq, bv, u, v2, cw);
  k_gemm_M<<<dim3(36), dim3(256), 0, stream>>>(Wk, Wq, Mt);
  k_gemm_G<<<dim3(96), dim3(256), 0, stream>>>(fact, Mt, Gb);
  k_lawprep<<<dim3(824), dim3(256), 0, stream>>>(E, u, v2, cw, mask, vw, cb, pre ? Ebf : (short*)nullptr);
  if (pre){
    k_attn8<<<dim3(1648), dim3(512), 0, stream>>>(Gb, Ebf, vw, cb, Zp, Wp);
    k_reduce<<<dim3(824), dim3(256), 0, stream>>>(Zp, Wp, bdp, dws);
  } else {
    k_attn_fb<<<dim3(1648), dim3(256), 0, stream>>>(Gb, E, vw, cb, bdp, dws);
  }
  k_final<<<dim3(4), dim3(256), 0, stream>>>(dws, wlp, blp, Wa, ba, Wt, bt, out);
}

// Round 9
// 326.440 us; speedup vs baseline: 1.8984x; 1.2050x over previous
//
#include <hip/hip_runtime.h>

#define D_ 768
#define S_ 512
#define R_ 512
#define L_ 103
#define F_ 4
#define NACCU 119
#define NTERM 11

using short8  = __attribute__((ext_vector_type(8))) short;
using short4v = __attribute__((ext_vector_type(4))) short;
using f32x4   = __attribute__((ext_vector_type(4))) float;

__device__ __forceinline__ short f2bf(float x){
  unsigned u = __float_as_uint(x);
  unsigned r = (u + 0x7FFFu + ((u >> 16) & 1u)) >> 16;  // RNE
  return (short)r;
}

// async global->LDS, 16B per lane (global_load_lds_dwordx4)
__device__ __forceinline__ void gload16(const short* g, short* l){
  __builtin_amdgcn_global_load_lds(
      (const __attribute__((address_space(1))) void*)g,
      (__attribute__((address_space(3))) void*)l, 16, 0, 0);
}

#define SFENCE() __builtin_amdgcn_sched_barrier(0)
#define BAR()    __builtin_amdgcn_s_barrier()

// Shared MFMA inner step (used by fused front/mid + fallback)
__device__ __forceinline__ void mfma_tile(const short* As, const short* Bs, f32x4 (&acc)[4][4],
                                          int wr, int wc, int ln, int lh){
  #pragma unroll
  for (int half = 0; half < 2; ++half){
    short8 a[4], b[4];
    #pragma unroll
    for (int i = 0; i < 4; ++i){
      int row = wr * 64 + i * 16 + ln;
      int ch = (lh + half * 4) ^ (row & 7);
      a[i] = *reinterpret_cast<const short8*>(&As[row * 64 + ch * 8]);
    }
    #pragma unroll
    for (int j = 0; j < 4; ++j){
      int row = wc * 64 + j * 16 + ln;
      int ch = (lh + half * 4) ^ (row & 7);
      b[j] = *reinterpret_cast<const short8*>(&Bs[row * 64 + ch * 8]);
    }
    #pragma unroll
    for (int i = 0; i < 4; ++i)
      #pragma unroll
      for (int j = 0; j < 4; ++j)
        acc[i][j] = __builtin_amdgcn_mfma_f32_16x16x32_bf16(a[i], b[j], acc[i][j], 0, 0, 0);
  }
}

// ---------------- K1 (fused): blocks 0-35 -> Mt = Wk^T Wq; blocks 36-39 -> prep ----------------
__global__ __launch_bounds__(256) void k_front(const float* __restrict__ Wk, const float* __restrict__ Wq,
      short* __restrict__ Mt,
      const float* __restrict__ Wv, const float* __restrict__ wd, const float* __restrict__ bq,
      const float* __restrict__ bv,
      float* __restrict__ u, float* __restrict__ v2, float* __restrict__ cw){
  __shared__ __align__(16) short As[128 * 64];
  __shared__ __align__(16) short Bs[128 * 64];
  int bid = blockIdx.x;
  int tid = threadIdx.x;
  if (bid >= 36){
    // ---- prep part (bid-36 in [0,4)) ----
    int pbid = bid - 36;
    if (pbid < 3){
      int d = pbid * 256 + tid;
      float su = 0.f, sv = 0.f;
      #pragma unroll 8
      for (int e = 0; e < D_; ++e){
        su = fmaf(Wv[e * D_ + d], wd[e], su);
        sv = fmaf(Wk[e * D_ + d], bq[e], sv);
      }
      u[d] = su; v2[d] = sv;
    } else {
      float* red = (float*)As;
      float p = bv[tid] * wd[tid] + bv[tid + 256] * wd[tid + 256] + bv[tid + 512] * wd[tid + 512];
      red[tid] = p;
      __syncthreads();
      for (int s = 128; s > 0; s >>= 1){
        if (tid < s) red[tid] += red[tid + s];
        __syncthreads();
      }
      if (tid == 0) cw[0] = red[0];
    }
    return;
  }
  // ---- gemm_M part: Mt[d',d] = sum_e Wk[e,d'] * Wq[e,d]  (bf16 out, linear) ----
  int m0 = (bid / 6) * 128, n0 = (bid % 6) * 128;
  int lane = tid & 63, wid = tid >> 6;
  int wr = wid >> 1, wc = wid & 1, ln = lane & 15, lh = lane >> 4;
  f32x4 acc[4][4];
  #pragma unroll
  for (int i = 0; i < 4; ++i)
    #pragma unroll
    for (int j = 0; j < 4; ++j)
      acc[i][j] = (f32x4){0.f, 0.f, 0.f, 0.f};
  int mm = (tid & 31) * 4;
  int kb = tid >> 5;   // 0..7
  for (int k0 = 0; k0 < D_; k0 += 64){
    #pragma unroll
    for (int ki = 0; ki < 8; ++ki){
      int k = kb + ki * 8;
      float4 va = *reinterpret_cast<const float4*>(&Wk[(k0 + k) * D_ + m0 + mm]);
      float4 vb = *reinterpret_cast<const float4*>(&Wq[(k0 + k) * D_ + n0 + mm]);
      As[(mm + 0) * 64 + ((ki ^ ((mm + 0) & 7)) * 8) + kb] = f2bf(va.x);
      As[(mm + 1) * 64 + ((ki ^ ((mm + 1) & 7)) * 8) + kb] = f2bf(va.y);
      As[(mm + 2) * 64 + ((ki ^ ((mm + 2) & 7)) * 8) + kb] = f2bf(va.z);
      As[(mm + 3) * 64 + ((ki ^ ((mm + 3) & 7)) * 8) + kb] = f2bf(va.w);
      Bs[(mm + 0) * 64 + ((ki ^ ((mm + 0) & 7)) * 8) + kb] = f2bf(vb.x);
      Bs[(mm + 1) * 64 + ((ki ^ ((mm + 1) & 7)) * 8) + kb] = f2bf(vb.y);
      Bs[(mm + 2) * 64 + ((ki ^ ((mm + 2) & 7)) * 8) + kb] = f2bf(vb.z);
      Bs[(mm + 3) * 64 + ((ki ^ ((mm + 3) & 7)) * 8) + kb] = f2bf(vb.w);
    }
    __syncthreads();
    mfma_tile(As, Bs, acc, wr, wc, ln, lh);
    __syncthreads();
  }
  #pragma unroll
  for (int i = 0; i < 4; ++i)
    #pragma unroll
    for (int j = 0; j < 4; ++j)
      #pragma unroll
      for (int rg = 0; rg < 4; ++rg){
        int row = m0 + wr * 64 + i * 16 + lh * 4 + rg;
        int col = n0 + wc * 64 + j * 16 + ln;
        Mt[row * D_ + col] = f2bf(acc[i][j][rg]);
      }
}

// ---------------- K2 (fused): blocks 0-95 -> Gb (pre-swizzled); 96-919 -> lawprep ----------------
__global__ __launch_bounds__(256) void k_mid(const float* __restrict__ A, const short* __restrict__ Mt,
      short* __restrict__ Gb,
      const float* __restrict__ E, const float* __restrict__ u, const float* __restrict__ v2,
      const float* __restrict__ cw, const float* __restrict__ mask,
      float* __restrict__ vw, float* __restrict__ cb, short* __restrict__ ebf){
  __shared__ __align__(16) short As[128 * 64];
  __shared__ __align__(16) short Bs[128 * 64];
  int bid = blockIdx.x;
  int tid = threadIdx.x;
  int lane = tid & 63;
  if (bid >= 96){
    // ---- lawprep part: vw[l,r], colbias[l,r]; E->bf16 PRE-SWIZZLED (2-row ILP) ----
    int w  = ((bid - 96) * 256 + tid) >> 6;
    int nw = (824 * 256) >> 6;
    float uu[12], vv[12];
    #pragma unroll
    for (int i = 0; i < 3; ++i){
      float4 a = *reinterpret_cast<const float4*>(&u[i * 256 + lane * 4]);
      float4 b = *reinterpret_cast<const float4*>(&v2[i * 256 + lane * 4]);
      uu[i*4+0] = a.x; uu[i*4+1] = a.y; uu[i*4+2] = a.z; uu[i*4+3] = a.w;
      vv[i*4+0] = b.x; vv[i*4+1] = b.y; vv[i*4+2] = b.z; vv[i*4+3] = b.w;
    }
    float c = cw[0];
    const float invsq = 0.03608439182435161f;
    int mid = (lane >> 1) & 7;
    int lo  = (lane & 1) * 4;
    int chiB = lane >> 4;
    for (int row = w * 2; row < L_ * R_; row += nw * 2){
      const float* e0 = E + (size_t)row * D_;
      const float* e1 = e0 + D_;
      int rs0 = row & 7, rs1 = (row + 1) & 7;
      float s1a = 0.f, s2a = 0.f, s1b = 0.f, s2b = 0.f;
      #pragma unroll
      for (int i = 0; i < 3; ++i){
        float4 ev0 = *reinterpret_cast<const float4*>(&e0[i * 256 + lane * 4]);
        float4 ev1 = *reinterpret_cast<const float4*>(&e1[i * 256 + lane * 4]);
        s1a = fmaf(ev0.x, uu[i*4+0], fmaf(ev0.y, uu[i*4+1], fmaf(ev0.z, uu[i*4+2], fmaf(ev0.w, uu[i*4+3], s1a))));
        s2a = fmaf(ev0.x, vv[i*4+0], fmaf(ev0.y, vv[i*4+1], fmaf(ev0.z, vv[i*4+2], fmaf(ev0.w, vv[i*4+3], s2a))));
        s1b = fmaf(ev1.x, uu[i*4+0], fmaf(ev1.y, uu[i*4+1], fmaf(ev1.z, uu[i*4+2], fmaf(ev1.w, uu[i*4+3], s1b))));
        s2b = fmaf(ev1.x, vv[i*4+0], fmaf(ev1.y, vv[i*4+1], fmaf(ev1.z, vv[i*4+2], fmaf(ev1.w, vv[i*4+3], s2b))));
        if (ebf){
          short4v p0, p1;
          p0[0] = f2bf(ev0.x); p0[1] = f2bf(ev0.y); p0[2] = f2bf(ev0.z); p0[3] = f2bf(ev0.w);
          p1[0] = f2bf(ev1.x); p1[1] = f2bf(ev1.y); p1[2] = f2bf(ev1.z); p1[3] = f2bf(ev1.w);
          int chi = i * 4 + chiB;
          *reinterpret_cast<short4v*>(&ebf[(size_t)row * D_ + chi * 64 + ((mid ^ rs0) << 3) + lo]) = p0;
          *reinterpret_cast<short4v*>(&ebf[(size_t)(row + 1) * D_ + chi * 64 + ((mid ^ rs1) << 3) + lo]) = p1;
        }
      }
      #pragma unroll
      for (int st = 1; st < 64; st <<= 1){
        s1a += __shfl_xor(s1a, st, 64);
        s2a += __shfl_xor(s2a, st, 64);
        s1b += __shfl_xor(s1b, st, 64);
        s2b += __shfl_xor(s2b, st, 64);
      }
      if (lane == 0){
        vw[row] = s1a + c;
        cb[row] = fmaf(s2a, invsq, mask[row]);
        vw[row + 1] = s1b + c;
        cb[row + 1] = fmaf(s2b, invsq, mask[row + 1]);
      }
    }
    return;
  }
  // ---- gemm_G part: G[t,d'] = sum_d fact[t,d] * Mt[d',d]  (bf16 out, PRE-SWIZZLED) ----
  int m0 = (bid / 6) * 128, n0 = (bid % 6) * 128;
  int wid = tid >> 6;
  int wr = wid >> 1, wc = wid & 1, ln = lane & 15, lh = lane >> 4;
  f32x4 acc[4][4];
  #pragma unroll
  for (int i = 0; i < 4; ++i)
    #pragma unroll
    for (int j = 0; j < 4; ++j)
      acc[i][j] = (f32x4){0.f, 0.f, 0.f, 0.f};
  int srow = tid >> 1, hf = tid & 1;
  int swz = srow & 7;
  const float* ap = A  + (size_t)(m0 + srow) * D_;
  const short* bp = Mt + (size_t)(n0 + srow) * D_;
  for (int k0 = 0; k0 < D_; k0 += 64){
    #pragma unroll
    for (int q = 0; q < 8; ++q){
      int k = hf * 32 + q * 4;
      float4 v = *reinterpret_cast<const float4*>(&ap[k0 + k]);
      short4v p; p[0] = f2bf(v.x); p[1] = f2bf(v.y); p[2] = f2bf(v.z); p[3] = f2bf(v.w);
      *reinterpret_cast<short4v*>(&As[srow * 64 + (((k >> 3) ^ swz) * 8) + (k & 7)]) = p;
    }
    #pragma unroll
    for (int q = 0; q < 4; ++q){
      int k = hf * 32 + q * 8;
      short8 v = *reinterpret_cast<const short8*>(&bp[k0 + k]);
      *reinterpret_cast<short8*>(&Bs[srow * 64 + (((k >> 3) ^ swz) * 8)]) = v;
    }
    __syncthreads();
    mfma_tile(As, Bs, acc, wr, wc, ln, lh);
    __syncthreads();
  }
  // store pre-swizzled: Gb[row][chi, mid ^ (row&7), lo] = value at (row, col)
  #pragma unroll
  for (int i = 0; i < 4; ++i)
    #pragma unroll
    for (int j = 0; j < 4; ++j)
      #pragma unroll
      for (int rg = 0; rg < 4; ++rg){
        int row = m0 + wr * 64 + i * 16 + lh * 4 + rg;
        int col = n0 + wc * 64 + j * 16 + ln;
        int chi = col >> 6, mid2 = (col >> 3) & 7, lo2 = col & 7;
        Gb[row * D_ + chi * 64 + ((mid2 ^ (row & 7)) << 3) + lo2] = f2bf(acc[i][j][rg]);
      }
}

// -------- helpers for the 1-barrier attn kernel --------
__device__ __forceinline__ void rd4f(const short* base, int rowBase, int ln, int lh, short8 (&d)[2][4]){
  #pragma unroll
  for (int ks = 0; ks < 2; ++ks)
    #pragma unroll
    for (int i = 0; i < 4; ++i){
      int row = rowBase + i * 16 + ln;
      int ch = (ks * 4 + lh) ^ (row & 7);
      d[ks][i] = *reinterpret_cast<const short8*>(&base[row * 64 + ch * 8]);
    }
}
__device__ __forceinline__ void rd2f(const short* base, int rowBase, int ln, int lh, short8 (&d)[2][2]){
  #pragma unroll
  for (int ks = 0; ks < 2; ++ks)
    #pragma unroll
    for (int j = 0; j < 2; ++j){
      int row = rowBase + j * 16 + ln;
      int ch = (ks * 4 + lh) ^ (row & 7);
      d[ks][j] = *reinterpret_cast<const short8*>(&base[row * 64 + ch * 8]);
    }
}
__device__ __forceinline__ void mm42(const short8 (&a)[2][4], const short8 (&b)[2][2],
                                     f32x4 (&acc)[8][4], int mo, int no){
  __builtin_amdgcn_s_setprio(1);
  #pragma unroll
  for (int ks = 0; ks < 2; ++ks)
    #pragma unroll
    for (int i = 0; i < 4; ++i)
      #pragma unroll
      for (int j = 0; j < 2; ++j)
        acc[mo + i][no + j] = __builtin_amdgcn_mfma_f32_16x16x32_bf16(a[ks][i], b[ks][j], acc[mo + i][no + j], 0, 0, 0);
  __builtin_amdgcn_s_setprio(0);
}

// ---------------- K5 v4 (R8-proven): 1 barrier/K-tile, zero intra-tile fences ----------------
__global__ __launch_bounds__(512, 2) void k_attn8(const short* __restrict__ Gb,
      const short* __restrict__ Ebf, const float* __restrict__ vw, const float* __restrict__ cbg,
      float* __restrict__ Zp, float* __restrict__ Wp){
  __shared__ __align__(16) short As[2][16384];
  __shared__ __align__(16) short Bs[2][16384];
  int b0 = blockIdx.x;
  int bid = (b0 & 7) * 206 + (b0 >> 3);     // 1648 = 8*206, bijective
  int l  = bid >> 4;
  int mt = (bid >> 1) & 7;
  int nt = bid & 1;
  int m0 = mt * 256, n0 = nt * 256;
  int tid = threadIdx.x, lane = tid & 63, wid = tid >> 6;
  int wr = wid >> 2, wc = wid & 3, ln = lane & 15, lh = lane >> 4;
  int c0 = tid, c1 = tid + 512;
  const short* gA0 = Gb  + (size_t)(m0 + (c0 >> 3)) * D_ + (c0 & 7) * 8;
  const short* gA1 = Gb  + (size_t)(m0 + (c1 >> 3)) * D_ + (c1 & 7) * 8;
  const short* gB0 = Ebf + (size_t)(l * R_ + n0 + (c0 >> 3)) * D_ + (c0 & 7) * 8;
  const short* gB1 = Ebf + (size_t)(l * R_ + n0 + (c1 >> 3)) * D_ + (c1 & 7) * 8;

  f32x4 acc[8][4];
  #pragma unroll
  for (int i = 0; i < 8; ++i)
    #pragma unroll
    for (int j = 0; j < 4; ++j)
      acc[i][j] = (f32x4){0.f, 0.f, 0.f, 0.f};

  #define STG_AB(t) { \
    short* da_ = &As[(t) & 1][0]; short* db_ = &Bs[(t) & 1][0]; \
    gload16(gA0 + (t) * 64, da_ + c0 * 8); \
    gload16(gA1 + (t) * 64, da_ + c1 * 8); \
    gload16(gA0 + (size_t)128 * D_ + (t) * 64, da_ + 8192 + c0 * 8); \
    gload16(gA1 + (size_t)128 * D_ + (t) * 64, da_ + 8192 + c1 * 8); \
    gload16(gB0 + (t) * 64, db_ + c0 * 8); \
    gload16(gB1 + (t) * 64, db_ + c1 * 8); \
    gload16(gB0 + (size_t)128 * D_ + (t) * 64, db_ + 8192 + c0 * 8); \
    gload16(gB1 + (size_t)128 * D_ + (t) * 64, db_ + 8192 + c1 * 8); }

  // prologue: tile 0 staged, drained, visible
  STG_AB(0);
  asm volatile("s_waitcnt vmcnt(0)" ::: "memory");
  BAR(); SFENCE();

  #pragma unroll 2
  for (int t = 0; t < 12; ++t){
    if (t + 1 < 12) STG_AB(t + 1);
    SFENCE();   // pin STG issue before the compute region (issue-early)
    const short* Asl = As[t & 1];
    const short* Bsl = Bs[t & 1];
    short8 a03[2][4], a47[2][4], b01[2][2], b23[2][2];
    rd4f(Asl, wr * 128, ln, lh, a03);
    rd2f(Bsl, wc * 64, ln, lh, b01);
    mm42(a03, b01, acc, 0, 0);
    rd4f(Asl, wr * 128 + 64, ln, lh, a47);
    mm42(a47, b01, acc, 4, 0);
    rd2f(Bsl, wc * 64 + 32, ln, lh, b23);
    mm42(a47, b23, acc, 4, 2);
    mm42(a03, b23, acc, 0, 2);
    asm volatile("s_waitcnt vmcnt(0)" ::: "memory");
    BAR(); SFENCE();
  }
  #undef STG_AB

  // epilogue: p = exp(score/sqrtD + colbias); Z/W partials over this block's 256 cols
  const float invsq = 0.03608439182435161f;
  float vwv[4], cbl[4];
  #pragma unroll
  for (int nj = 0; nj < 4; ++nj){
    int r = l * R_ + n0 + wc * 64 + nj * 16 + ln;
    vwv[nj] = vw[r];
    cbl[nj] = cbg[r];
  }
  float* zr  = (float*)&As[0][0];   // [4][256]
  float* wrd = zr + 1024;           // [4][256]
  #pragma unroll
  for (int mi = 0; mi < 8; ++mi){
    #pragma unroll
    for (int rg = 0; rg < 4; ++rg){
      float z = 0.f, w = 0.f;
      #pragma unroll
      for (int nj = 0; nj < 4; ++nj){
        float p = __expf(fmaf(acc[mi][nj][rg], invsq, cbl[nj]));
        z += p;
        w = fmaf(p, vwv[nj], w);
      }
      z += __shfl_xor(z, 1, 64); w += __shfl_xor(w, 1, 64);
      z += __shfl_xor(z, 2, 64); w += __shfl_xor(w, 2, 64);
      z += __shfl_xor(z, 4, 64); w += __shfl_xor(w, 4, 64);
      z += __shfl_xor(z, 8, 64); w += __shfl_xor(w, 8, 64);
      if (ln == 0){
        int row = wr * 128 + mi * 16 + lh * 4 + rg;
        zr[wc * 256 + row] = z;
        wrd[wc * 256 + row] = w;
      }
    }
  }
  __syncthreads();
  if (tid < 256){
    float z = zr[tid] + zr[256 + tid] + zr[512 + tid] + zr[768 + tid];
    float w = wrd[tid] + wrd[256 + tid] + wrd[512 + tid] + wrd[768 + tid];
    size_t o = (size_t)(l * 2 + nt) * 2048 + m0 + tid;
    Zp[o] = z;
    Wp[o] = w;
  }
}

// ---------------- K5b: combine N-halves -> d ----------------
__global__ __launch_bounds__(256) void k_reduce(const float* __restrict__ Zp, const float* __restrict__ Wp,
      const float* __restrict__ bdp, float* __restrict__ dws){
  int idx = blockIdx.x * 256 + threadIdx.x;
  float b = bdp[0];
  for (int i = idx; i < L_ * 2048; i += gridDim.x * 256){
    int l = i >> 11, g = i & 2047;
    int f = g >> 9, s = g & 511;
    float z = Zp[(size_t)(l * 2) * 2048 + g] + Zp[(size_t)(l * 2 + 1) * 2048 + g];
    float w = Wp[(size_t)(l * 2) * 2048 + g] + Wp[(size_t)(l * 2 + 1) * 2048 + g];
    dws[(size_t)(f * L_ + l) * S_ + s] = w / z + b;
  }
}

// ---------------- K5 fallback (ws too small for Ebf; dead in practice) ----------------
__global__ __launch_bounds__(256) void k_attn_fb(const short* __restrict__ Gb, const float* __restrict__ E,
      const float* __restrict__ vw, const float* __restrict__ cbg,
      const float* __restrict__ bdp, float* __restrict__ dws){
  __shared__ __align__(16) short As[128 * 64];
  __shared__ __align__(16) short Bs[128 * 64];
  __shared__ float mM[2][128], mZ[2][128], mW[2][128];
  int b0 = blockIdx.x;
  int bid = (b0 & 7) * 206 + (b0 >> 3);
  int l  = bid >> 4;
  int f  = (bid >> 2) & 3;
  int sc = bid & 3;
  int s0 = sc * 128;
  int tid = threadIdx.x, lane = tid & 63, wid = tid >> 6;
  int wr = wid >> 1, wc = wid & 1, ln = lane & 15, lh = lane >> 4;
  const float invsq = 0.03608439182435161f;
  float sm_m[16], sm_z[16], sm_w[16];
  #pragma unroll
  for (int i = 0; i < 16; ++i){ sm_m[i] = -3.0e38f; sm_z[i] = 0.f; sm_w[i] = 0.f; }
  int srow = tid >> 1, hf = tid & 1;
  int swz = srow & 7;
  const short* gp = Gb + (size_t)(f * S_ + s0 + srow) * D_;
  for (int rt = 0; rt < 4; ++rt){
    f32x4 acc[4][4];
    #pragma unroll
    for (int i = 0; i < 4; ++i)
      #pragma unroll
      for (int j = 0; j < 4; ++j)
        acc[i][j] = (f32x4){0.f, 0.f, 0.f, 0.f};
    const float* ep = E + (size_t)(l * R_ + rt * 128 + srow) * D_;
    for (int k0 = 0; k0 < D_; k0 += 64){
      // Gb is pre-swizzled; copy linearly (chunks land swizzle-consistent)
      #pragma unroll
      for (int q = 0; q < 4; ++q){
        int k = hf * 32 + q * 8;
        short8 v = *reinterpret_cast<const short8*>(&gp[k0 + k]);
        *reinterpret_cast<short8*>(&As[srow * 64 + k]) = v;
      }
      #pragma unroll
      for (int q = 0; q < 4; ++q){
        int k = hf * 32 + q * 8;
        float4 v0 = *reinterpret_cast<const float4*>(&ep[k0 + k]);
        float4 v1 = *reinterpret_cast<const float4*>(&ep[k0 + k + 4]);
        short8 p;
        p[0] = f2bf(v0.x); p[1] = f2bf(v0.y); p[2] = f2bf(v0.z); p[3] = f2bf(v0.w);
        p[4] = f2bf(v1.x); p[5] = f2bf(v1.y); p[6] = f2bf(v1.z); p[7] = f2bf(v1.w);
        *reinterpret_cast<short8*>(&Bs[srow * 64 + (((k >> 3) ^ swz) * 8)]) = p;
      }
      __syncthreads();
      mfma_tile(As, Bs, acc, wr, wc, ln, lh);
      __syncthreads();
    }
    float vwv[4], cbl[4];
    #pragma unroll
    for (int j = 0; j < 4; ++j){
      int r = l * R_ + rt * 128 + wc * 64 + j * 16 + ln;
      vwv[j] = vw[r];
      cbl[j] = cbg[r];
    }
    #pragma unroll
    for (int i = 0; i < 4; ++i){
      #pragma unroll
      for (int rg = 0; rg < 4; ++rg){
        float v0 = fmaf(acc[i][0][rg], invsq, cbl[0]);
        float v1 = fmaf(acc[i][1][rg], invsq, cbl[1]);
        float v2 = fmaf(acc[i][2][rg], invsq, cbl[2]);
        float v3 = fmaf(acc[i][3][rg], invsq, cbl[3]);
        float tm = fmaxf(fmaxf(v0, v1), fmaxf(v2, v3));
        int idx = i * 4 + rg;
        float mo = sm_m[idx];
        float nm = fmaxf(mo, tm);
        float scl = __expf(mo - nm);
        float p0 = __expf(v0 - nm), p1 = __expf(v1 - nm);
        float p2 = __expf(v2 - nm), p3 = __expf(v3 - nm);
        sm_z[idx] = fmaf(sm_z[idx], scl, (p0 + p1) + (p2 + p3));
        sm_w[idx] = fmaf(sm_w[idx], scl, fmaf(p0, vwv[0], fmaf(p1, vwv[1], fmaf(p2, vwv[2], p3 * vwv[3]))));
        sm_m[idx] = nm;
      }
    }
  }
  #pragma unroll
  for (int st = 1; st < 16; st <<= 1){
    #pragma unroll
    for (int idx = 0; idx < 16; ++idx){
      float om = __shfl_xor(sm_m[idx], st, 64);
      float oz = __shfl_xor(sm_z[idx], st, 64);
      float ow = __shfl_xor(sm_w[idx], st, 64);
      float nm = fmaxf(sm_m[idx], om);
      float e1 = __expf(sm_m[idx] - nm);
      float e2 = __expf(om - nm);
      sm_z[idx] = fmaf(sm_z[idx], e1, oz * e2);
      sm_w[idx] = fmaf(sm_w[idx], e1, ow * e2);
      sm_m[idx] = nm;
    }
  }
  if (ln == 0){
    #pragma unroll
    for (int i = 0; i < 4; ++i)
      #pragma unroll
      for (int rg = 0; rg < 4; ++rg){
        int row = wr * 64 + i * 16 + lh * 4 + rg;
        int idx = i * 4 + rg;
        mM[wc][row] = sm_m[idx]; mZ[wc][row] = sm_z[idx]; mW[wc][row] = sm_w[idx];
      }
  }
  __syncthreads();
  if (tid < 128){
    float ma = mM[0][tid], mb = mM[1][tid];
    float nm = fmaxf(ma, mb);
    float ea = __expf(ma - nm), eb = __expf(mb - nm);
    float z = mZ[0][tid] * ea + mZ[1][tid] * eb;
    float w = mW[0][tid] * ea + mW[1][tid] * eb;
    dws[(size_t)(f * L_ + l) * S_ + s0 + tid] = w / z + bdp[0];
  }
}

// ---------------- K6: law, accu, term ----------------
__global__ __launch_bounds__(256) void k_final(const float* __restrict__ dws, const float* __restrict__ wlp,
      const float* __restrict__ blp, const float* __restrict__ Wa, const float* __restrict__ ba,
      const float* __restrict__ Wt, const float* __restrict__ bt, float* __restrict__ out){
  int f = blockIdx.x, tid = threadIdx.x;
  __shared__ float lawf[L_];
  if (tid < L_){
    const float* dp = dws + (size_t)(f * L_ + tid) * S_;
    float s = 0.f;
    #pragma unroll 4
    for (int i = 0; i < S_; i += 4){
      float4 v  = *reinterpret_cast<const float4*>(&dp[i]);
      float4 wv = *reinterpret_cast<const float4*>(&wlp[i]);
      s = fmaf(v.x, wv.x, fmaf(v.y, wv.y, fmaf(v.z, wv.z, fmaf(v.w, wv.w, s))));
    }
    s += blp[0];
    out[f * L_ + tid] = s;
    lawf[tid] = s;
  }
  __syncthreads();
  if (tid < NACCU){
    float s = ba[tid];
    for (int ll = 0; ll < L_; ++ll) s = fmaf(lawf[ll], Wa[tid * L_ + ll], s);
    out[F_ * L_ + f * NACCU + tid] = s;
  }
  if (tid >= 128 && tid < 128 + NTERM){
    int t = tid - 128;
    float s = bt[t];
    for (int ll = 0; ll < L_; ++ll) s = fmaf(lawf[ll], Wt[t * L_ + ll], s);
    out[F_ * L_ + F_ * NACCU + f * NTERM + t] = s;
  }
}

extern "C" void kernel_launch(void* const* d_in, const int* in_sizes, int n_in,
                              void* d_out, int out_size, void* d_ws, size_t ws_size,
                              hipStream_t stream){
  (void)in_sizes; (void)n_in; (void)out_size;
  const float* fact = (const float*)d_in[0];
  const float* E    = (const float*)d_in[1];
  const float* Wq   = (const float*)d_in[2];
  const float* bq   = (const float*)d_in[3];
  const float* Wk   = (const float*)d_in[4];
  const float* bk   = (const float*)d_in[5];
  const float* Wv   = (const float*)d_in[6];
  const float* bv   = (const float*)d_in[7];
  const float* wd   = (const float*)d_in[8];
  const float* bdp  = (const float*)d_in[9];
  const float* wlp  = (const float*)d_in[10];
  const float* blp  = (const float*)d_in[11];
  const float* Wa   = (const float*)d_in[12];
  const float* ba   = (const float*)d_in[13];
  const float* Wt   = (const float*)d_in[14];
  const float* bt   = (const float*)d_in[15];
  const float* mask = (const float*)d_in[16];
  (void)bk;
  char* ws = (char*)d_ws;
  float* u   = (float*)(ws + 0);
  float* v2  = (float*)(ws + 3072);
  float* cw  = (float*)(ws + 6144);
  short* Mt  = (short*)(ws + 6400);
  short* Gb  = (short*)(ws + 1186048);
  float* vw  = (float*)(ws + 4331776);
  float* cb  = (float*)(ws + 4542720);
  float* dws = (float*)(ws + 4753664);
  short* Ebf = (short*)(ws + 5597440);
  float* Zp  = (float*)(ws + 86599936);
  float* Wp  = (float*)(ws + 88287488);
  const size_t need2 = 89975040ULL;
  bool pre = ws_size >= need2;
  float* out = (float*)d_out;

  k_front<<<dim3(40), dim3(256), 0, stream>>>(Wk, Wq, Mt, Wv, wd, bq, bv, u, v2, cw);
  k_mid<<<dim3(920), dim3(256), 0, stream>>>(fact, Mt, Gb, E, u, v2, cw, mask, vw, cb,
                                             pre ? Ebf : (short*)nullptr);
  if (pre){
    k_attn8<<<dim3(1648), dim3(512), 0, stream>>>(Gb, Ebf, vw, cb, Zp, Wp);
    k_reduce<<<dim3(824), dim3(256), 0, stream>>>(Zp, Wp, bdp, dws);
  } else {
    k_attn_fb<<<dim3(1648), dim3(256), 0, stream>>>(Gb, E, vw, cb, bdp, dws);
  }
  k_final<<<dim3(4), dim3(256), 0, stream>>>(dws, wlp, blp, Wa, ba, Wt, bt, out);
}

// Round 11
// 297.580 us; speedup vs baseline: 2.0825x; 1.0970x over previous
//
#include <hip/hip_runtime.h>

#define D_ 768
#define S_ 512
#define R_ 512
#define L_ 103
#define F_ 4
#define NACCU 119
#define NTERM 11

using short8  = __attribute__((ext_vector_type(8))) short;
using short4v = __attribute__((ext_vector_type(4))) short;
using f32x4   = __attribute__((ext_vector_type(4))) float;

__device__ __forceinline__ short f2bf(float x){
  unsigned u = __float_as_uint(x);
  unsigned r = (u + 0x7FFFu + ((u >> 16) & 1u)) >> 16;  // RNE
  return (short)r;
}

// async global->LDS, 16B per lane (global_load_lds_dwordx4)
__device__ __forceinline__ void gload16(const short* g, short* l){
  __builtin_amdgcn_global_load_lds(
      (const __attribute__((address_space(1))) void*)g,
      (__attribute__((address_space(3))) void*)l, 16, 0, 0);
}

#define SFENCE() __builtin_amdgcn_sched_barrier(0)
#define BAR()    __builtin_amdgcn_s_barrier()

// 16-lane rotate-reduce on the VALU pipe (DPP row_ror) - ctrl must be a literal constant,
// so it is a template parameter (R10 compile-error lesson).
template<int CTRL>
__device__ __forceinline__ float ror_add(float x){
  int t = __builtin_amdgcn_update_dpp(0, __float_as_int(x), CTRL, 0xF, 0xF, false);
  return x + __int_as_float(t);
}
__device__ __forceinline__ float sum16(float x){
  x = ror_add<0x128>(x);  // row_ror:8
  x = ror_add<0x124>(x);  // row_ror:4
  x = ror_add<0x122>(x);  // row_ror:2
  x = ror_add<0x121>(x);  // row_ror:1
  return x;
}

// Shared MFMA inner step (used by fused front/mid + fallback)
__device__ __forceinline__ void mfma_tile(const short* As, const short* Bs, f32x4 (&acc)[4][4],
                                          int wr, int wc, int ln, int lh){
  #pragma unroll
  for (int half = 0; half < 2; ++half){
    short8 a[4], b[4];
    #pragma unroll
    for (int i = 0; i < 4; ++i){
      int row = wr * 64 + i * 16 + ln;
      int ch = (lh + half * 4) ^ (row & 7);
      a[i] = *reinterpret_cast<const short8*>(&As[row * 64 + ch * 8]);
    }
    #pragma unroll
    for (int j = 0; j < 4; ++j){
      int row = wc * 64 + j * 16 + ln;
      int ch = (lh + half * 4) ^ (row & 7);
      b[j] = *reinterpret_cast<const short8*>(&Bs[row * 64 + ch * 8]);
    }
    #pragma unroll
    for (int i = 0; i < 4; ++i)
      #pragma unroll
      for (int j = 0; j < 4; ++j)
        acc[i][j] = __builtin_amdgcn_mfma_f32_16x16x32_bf16(a[i], b[j], acc[i][j], 0, 0, 0);
  }
}

// ---------------- K1 (fused): blocks 0-35 -> Mt = Wk^T Wq; blocks 36-39 -> prep ----------------
__global__ __launch_bounds__(256) void k_front(const float* __restrict__ Wk, const float* __restrict__ Wq,
      short* __restrict__ Mt,
      const float* __restrict__ Wv, const float* __restrict__ wd, const float* __restrict__ bq,
      const float* __restrict__ bv,
      float* __restrict__ u, float* __restrict__ v2, float* __restrict__ cw){
  __shared__ __align__(16) short As[128 * 64];
  __shared__ __align__(16) short Bs[128 * 64];
  int bid = blockIdx.x;
  int tid = threadIdx.x;
  if (bid >= 36){
    int pbid = bid - 36;
    if (pbid < 3){
      int d = pbid * 256 + tid;
      float su = 0.f, sv = 0.f;
      #pragma unroll 8
      for (int e = 0; e < D_; ++e){
        su = fmaf(Wv[e * D_ + d], wd[e], su);
        sv = fmaf(Wk[e * D_ + d], bq[e], sv);
      }
      u[d] = su; v2[d] = sv;
    } else {
      float* red = (float*)As;
      float p = bv[tid] * wd[tid] + bv[tid + 256] * wd[tid + 256] + bv[tid + 512] * wd[tid + 512];
      red[tid] = p;
      __syncthreads();
      for (int s = 128; s > 0; s >>= 1){
        if (tid < s) red[tid] += red[tid + s];
        __syncthreads();
      }
      if (tid == 0) cw[0] = red[0];
    }
    return;
  }
  int m0 = (bid / 6) * 128, n0 = (bid % 6) * 128;
  int lane = tid & 63, wid = tid >> 6;
  int wr = wid >> 1, wc = wid & 1, ln = lane & 15, lh = lane >> 4;
  f32x4 acc[4][4];
  #pragma unroll
  for (int i = 0; i < 4; ++i)
    #pragma unroll
    for (int j = 0; j < 4; ++j)
      acc[i][j] = (f32x4){0.f, 0.f, 0.f, 0.f};
  int mm = (tid & 31) * 4;
  int kb = tid >> 5;   // 0..7
  for (int k0 = 0; k0 < D_; k0 += 64){
    #pragma unroll
    for (int ki = 0; ki < 8; ++ki){
      int k = kb + ki * 8;
      float4 va = *reinterpret_cast<const float4*>(&Wk[(k0 + k) * D_ + m0 + mm]);
      float4 vb = *reinterpret_cast<const float4*>(&Wq[(k0 + k) * D_ + n0 + mm]);
      As[(mm + 0) * 64 + ((ki ^ ((mm + 0) & 7)) * 8) + kb] = f2bf(va.x);
      As[(mm + 1) * 64 + ((ki ^ ((mm + 1) & 7)) * 8) + kb] = f2bf(va.y);
      As[(mm + 2) * 64 + ((ki ^ ((mm + 2) & 7)) * 8) + kb] = f2bf(va.z);
      As[(mm + 3) * 64 + ((ki ^ ((mm + 3) & 7)) * 8) + kb] = f2bf(va.w);
      Bs[(mm + 0) * 64 + ((ki ^ ((mm + 0) & 7)) * 8) + kb] = f2bf(vb.x);
      Bs[(mm + 1) * 64 + ((ki ^ ((mm + 1) & 7)) * 8) + kb] = f2bf(vb.y);
      Bs[(mm + 2) * 64 + ((ki ^ ((mm + 2) & 7)) * 8) + kb] = f2bf(vb.z);
      Bs[(mm + 3) * 64 + ((ki ^ ((mm + 3) & 7)) * 8) + kb] = f2bf(vb.w);
    }
    __syncthreads();
    mfma_tile(As, Bs, acc, wr, wc, ln, lh);
    __syncthreads();
  }
  #pragma unroll
  for (int i = 0; i < 4; ++i)
    #pragma unroll
    for (int j = 0; j < 4; ++j)
      #pragma unroll
      for (int rg = 0; rg < 4; ++rg){
        int row = m0 + wr * 64 + i * 16 + lh * 4 + rg;
        int col = n0 + wc * 64 + j * 16 + ln;
        Mt[row * D_ + col] = f2bf(acc[i][j][rg]);
      }
}

// ---------------- K2 (fused): blocks 0-95 -> Gb (pre-swizzled); 96-919 -> lawprep ----------------
__global__ __launch_bounds__(256) void k_mid(const float* __restrict__ A, const short* __restrict__ Mt,
      short* __restrict__ Gb,
      const float* __restrict__ E, const float* __restrict__ u, const float* __restrict__ v2,
      const float* __restrict__ cw, const float* __restrict__ mask,
      float* __restrict__ vw, float* __restrict__ cb, short* __restrict__ ebf){
  __shared__ __align__(16) short As[128 * 64];
  __shared__ __align__(16) short Bs[128 * 64];
  int bid = blockIdx.x;
  int tid = threadIdx.x;
  int lane = tid & 63;
  if (bid >= 96){
    int w  = ((bid - 96) * 256 + tid) >> 6;
    int nw = (824 * 256) >> 6;
    float uu[12], vv[12];
    #pragma unroll
    for (int i = 0; i < 3; ++i){
      float4 a = *reinterpret_cast<const float4*>(&u[i * 256 + lane * 4]);
      float4 b = *reinterpret_cast<const float4*>(&v2[i * 256 + lane * 4]);
      uu[i*4+0] = a.x; uu[i*4+1] = a.y; uu[i*4+2] = a.z; uu[i*4+3] = a.w;
      vv[i*4+0] = b.x; vv[i*4+1] = b.y; vv[i*4+2] = b.z; vv[i*4+3] = b.w;
    }
    float c = cw[0];
    const float invsq = 0.03608439182435161f;
    int mid = (lane >> 1) & 7;
    int lo  = (lane & 1) * 4;
    int chiB = lane >> 4;
    for (int row = w * 2; row < L_ * R_; row += nw * 2){
      const float* e0 = E + (size_t)row * D_;
      const float* e1 = e0 + D_;
      int rs0 = row & 7, rs1 = (row + 1) & 7;
      float s1a = 0.f, s2a = 0.f, s1b = 0.f, s2b = 0.f;
      #pragma unroll
      for (int i = 0; i < 3; ++i){
        float4 ev0 = *reinterpret_cast<const float4*>(&e0[i * 256 + lane * 4]);
        float4 ev1 = *reinterpret_cast<const float4*>(&e1[i * 256 + lane * 4]);
        s1a = fmaf(ev0.x, uu[i*4+0], fmaf(ev0.y, uu[i*4+1], fmaf(ev0.z, uu[i*4+2], fmaf(ev0.w, uu[i*4+3], s1a))));
        s2a = fmaf(ev0.x, vv[i*4+0], fmaf(ev0.y, vv[i*4+1], fmaf(ev0.z, vv[i*4+2], fmaf(ev0.w, vv[i*4+3], s2a))));
        s1b = fmaf(ev1.x, uu[i*4+0], fmaf(ev1.y, uu[i*4+1], fmaf(ev1.z, uu[i*4+2], fmaf(ev1.w, uu[i*4+3], s1b))));
        s2b = fmaf(ev1.x, vv[i*4+0], fmaf(ev1.y, vv[i*4+1], fmaf(ev1.z, vv[i*4+2], fmaf(ev1.w, vv[i*4+3], s2b))));
        if (ebf){
          short4v p0, p1;
          p0[0] = f2bf(ev0.x); p0[1] = f2bf(ev0.y); p0[2] = f2bf(ev0.z); p0[3] = f2bf(ev0.w);
          p1[0] = f2bf(ev1.x); p1[1] = f2bf(ev1.y); p1[2] = f2bf(ev1.z); p1[3] = f2bf(ev1.w);
          int chi = i * 4 + chiB;
          *reinterpret_cast<short4v*>(&ebf[(size_t)row * D_ + chi * 64 + ((mid ^ rs0) << 3) + lo]) = p0;
          *reinterpret_cast<short4v*>(&ebf[(size_t)(row + 1) * D_ + chi * 64 + ((mid ^ rs1) << 3) + lo]) = p1;
        }
      }
      #pragma unroll
      for (int st = 1; st < 64; st <<= 1){
        s1a += __shfl_xor(s1a, st, 64);
        s2a += __shfl_xor(s2a, st, 64);
        s1b += __shfl_xor(s1b, st, 64);
        s2b += __shfl_xor(s2b, st, 64);
      }
      if (lane == 0){
        vw[row] = s1a + c;
        cb[row] = fmaf(s2a, invsq, mask[row]);
        vw[row + 1] = s1b + c;
        cb[row + 1] = fmaf(s2b, invsq, mask[row + 1]);
      }
    }
    return;
  }
  int m0 = (bid / 6) * 128, n0 = (bid % 6) * 128;
  int wid = tid >> 6;
  int wr = wid >> 1, wc = wid & 1, ln = lane & 15, lh = lane >> 4;
  f32x4 acc[4][4];
  #pragma unroll
  for (int i = 0; i < 4; ++i)
    #pragma unroll
    for (int j = 0; j < 4; ++j)
      acc[i][j] = (f32x4){0.f, 0.f, 0.f, 0.f};
  int srow = tid >> 1, hf = tid & 1;
  int swz = srow & 7;
  const float* ap = A  + (size_t)(m0 + srow) * D_;
  const short* bp = Mt + (size_t)(n0 + srow) * D_;
  for (int k0 = 0; k0 < D_; k0 += 64){
    #pragma unroll
    for (int q = 0; q < 8; ++q){
      int k = hf * 32 + q * 4;
      float4 v = *reinterpret_cast<const float4*>(&ap[k0 + k]);
      short4v p; p[0] = f2bf(v.x); p[1] = f2bf(v.y); p[2] = f2bf(v.z); p[3] = f2bf(v.w);
      *reinterpret_cast<short4v*>(&As[srow * 64 + (((k >> 3) ^ swz) * 8) + (k & 7)]) = p;
    }
    #pragma unroll
    for (int q = 0; q < 4; ++q){
      int k = hf * 32 + q * 8;
      short8 v = *reinterpret_cast<const short8*>(&bp[k0 + k]);
      *reinterpret_cast<short8*>(&Bs[srow * 64 + (((k >> 3) ^ swz) * 8)]) = v;
    }
    __syncthreads();
    mfma_tile(As, Bs, acc, wr, wc, ln, lh);
    __syncthreads();
  }
  #pragma unroll
  for (int i = 0; i < 4; ++i)
    #pragma unroll
    for (int j = 0; j < 4; ++j)
      #pragma unroll
      for (int rg = 0; rg < 4; ++rg){
        int row = m0 + wr * 64 + i * 16 + lh * 4 + rg;
        int col = n0 + wc * 64 + j * 16 + ln;
        int chi = col >> 6, mid2 = (col >> 3) & 7, lo2 = col & 7;
        Gb[row * D_ + chi * 64 + ((mid2 ^ (row & 7)) << 3) + lo2] = f2bf(acc[i][j][rg]);
      }
}

// -------- helpers for the 1-barrier attn kernel --------
__device__ __forceinline__ void rd4f(const short* base, int rowBase, int ln, int lh, short8 (&d)[2][4]){
  #pragma unroll
  for (int ks = 0; ks < 2; ++ks)
    #pragma unroll
    for (int i = 0; i < 4; ++i){
      int row = rowBase + i * 16 + ln;
      int ch = (ks * 4 + lh) ^ (row & 7);
      d[ks][i] = *reinterpret_cast<const short8*>(&base[row * 64 + ch * 8]);
    }
}
__device__ __forceinline__ void rd2f(const short* base, int rowBase, int ln, int lh, short8 (&d)[2][2]){
  #pragma unroll
  for (int ks = 0; ks < 2; ++ks)
    #pragma unroll
    for (int j = 0; j < 2; ++j){
      int row = rowBase + j * 16 + ln;
      int ch = (ks * 4 + lh) ^ (row & 7);
      d[ks][j] = *reinterpret_cast<const short8*>(&base[row * 64 + ch * 8]);
    }
}
__device__ __forceinline__ void mm42(const short8 (&a)[2][4], const short8 (&b)[2][2],
                                     f32x4 (&acc)[8][4], int mo, int no){
  __builtin_amdgcn_s_setprio(1);
  #pragma unroll
  for (int ks = 0; ks < 2; ++ks)
    #pragma unroll
    for (int i = 0; i < 4; ++i)
      #pragma unroll
      for (int j = 0; j < 2; ++j)
        acc[mo + i][no + j] = __builtin_amdgcn_mfma_f32_16x16x32_bf16(a[ks][i], b[ks][j], acc[mo + i][no + j], 0, 0, 0);
  __builtin_amdgcn_s_setprio(0);
}

// ---------------- K5 v4 (R8-proven loop): 1 barrier/K-tile; DPP epilogue ----------------
__global__ __launch_bounds__(512, 2) void k_attn8(const short* __restrict__ Gb,
      const short* __restrict__ Ebf, const float* __restrict__ vw, const float* __restrict__ cbg,
      float* __restrict__ Zp, float* __restrict__ Wp){
  __shared__ __align__(16) short As[2][16384];
  __shared__ __align__(16) short Bs[2][16384];
  int b0 = blockIdx.x;
  int bid = (b0 & 7) * 206 + (b0 >> 3);     // 1648 = 8*206, bijective
  int l  = bid >> 4;
  int mt = (bid >> 1) & 7;
  int nt = bid & 1;
  int m0 = mt * 256, n0 = nt * 256;
  int tid = threadIdx.x, lane = tid & 63, wid = tid >> 6;
  int wr = wid >> 2, wc = wid & 3, ln = lane & 15, lh = lane >> 4;
  int c0 = tid, c1 = tid + 512;
  const short* gA0 = Gb  + (size_t)(m0 + (c0 >> 3)) * D_ + (c0 & 7) * 8;
  const short* gA1 = Gb  + (size_t)(m0 + (c1 >> 3)) * D_ + (c1 & 7) * 8;
  const short* gB0 = Ebf + (size_t)(l * R_ + n0 + (c0 >> 3)) * D_ + (c0 & 7) * 8;
  const short* gB1 = Ebf + (size_t)(l * R_ + n0 + (c1 >> 3)) * D_ + (c1 & 7) * 8;

  f32x4 acc[8][4];
  #pragma unroll
  for (int i = 0; i < 8; ++i)
    #pragma unroll
    for (int j = 0; j < 4; ++j)
      acc[i][j] = (f32x4){0.f, 0.f, 0.f, 0.f};

  #define STG_AB(t) { \
    short* da_ = &As[(t) & 1][0]; short* db_ = &Bs[(t) & 1][0]; \
    gload16(gA0 + (t) * 64, da_ + c0 * 8); \
    gload16(gA1 + (t) * 64, da_ + c1 * 8); \
    gload16(gA0 + (size_t)128 * D_ + (t) * 64, da_ + 8192 + c0 * 8); \
    gload16(gA1 + (size_t)128 * D_ + (t) * 64, da_ + 8192 + c1 * 8); \
    gload16(gB0 + (t) * 64, db_ + c0 * 8); \
    gload16(gB1 + (t) * 64, db_ + c1 * 8); \
    gload16(gB0 + (size_t)128 * D_ + (t) * 64, db_ + 8192 + c0 * 8); \
    gload16(gB1 + (size_t)128 * D_ + (t) * 64, db_ + 8192 + c1 * 8); }

  STG_AB(0);
  asm volatile("s_waitcnt vmcnt(0)" ::: "memory");
  BAR(); SFENCE();

  #pragma unroll 2
  for (int t = 0; t < 12; ++t){
    if (t + 1 < 12) STG_AB(t + 1);
    SFENCE();
    const short* Asl = As[t & 1];
    const short* Bsl = Bs[t & 1];
    short8 a03[2][4], a47[2][4], b01[2][2], b23[2][2];
    rd4f(Asl, wr * 128, ln, lh, a03);
    rd2f(Bsl, wc * 64, ln, lh, b01);
    mm42(a03, b01, acc, 0, 0);
    rd4f(Asl, wr * 128 + 64, ln, lh, a47);
    mm42(a47, b01, acc, 4, 0);
    rd2f(Bsl, wc * 64 + 32, ln, lh, b23);
    mm42(a47, b23, acc, 4, 2);
    mm42(a03, b23, acc, 0, 2);
    asm volatile("s_waitcnt vmcnt(0)" ::: "memory");
    BAR(); SFENCE();
  }
  #undef STG_AB

  // epilogue: p = exp(score/sqrtD + colbias); Z/W partials; DPP rotate-reduce (VALU pipe)
  const float invsq = 0.03608439182435161f;
  float vwv[4], cbl[4];
  #pragma unroll
  for (int nj = 0; nj < 4; ++nj){
    int r = l * R_ + n0 + wc * 64 + nj * 16 + ln;
    vwv[nj] = vw[r];
    cbl[nj] = cbg[r];
  }
  float* zr  = (float*)&As[0][0];   // [4][256]
  float* wrd = zr + 1024;           // [4][256]
  #pragma unroll
  for (int mi = 0; mi < 8; ++mi){
    #pragma unroll
    for (int rg = 0; rg < 4; ++rg){
      float z = 0.f, w = 0.f;
      #pragma unroll
      for (int nj = 0; nj < 4; ++nj){
        float p = __expf(fmaf(acc[mi][nj][rg], invsq, cbl[nj]));
        z += p;
        w = fmaf(p, vwv[nj], w);
      }
      z = sum16(z);
      w = sum16(w);
      if (ln == 0){
        int row = wr * 128 + mi * 16 + lh * 4 + rg;
        zr[wc * 256 + row] = z;
        wrd[wc * 256 + row] = w;
      }
    }
  }
  __syncthreads();
  if (tid < 256){
    float z = zr[tid] + zr[256 + tid] + zr[512 + tid] + zr[768 + tid];
    float w = wrd[tid] + wrd[256 + tid] + wrd[512 + tid] + wrd[768 + tid];
    size_t o = (size_t)(l * 2 + nt) * 2048 + m0 + tid;
    Zp[o] = z;
    Wp[o] = w;
  }
}

// ---------------- K5b: per-l law (d = w/z + b, dot with wlp) -> out, no dws round-trip ----------------
__global__ __launch_bounds__(256) void k_law(const float* __restrict__ Zp, const float* __restrict__ Wp,
      const float* __restrict__ bdp, const float* __restrict__ wlp, const float* __restrict__ blp,
      float* __restrict__ out){
  int l = blockIdx.x;
  int tid = threadIdx.x;
  int f = tid >> 6, lane = tid & 63;
  const float* z0 = Zp + (size_t)(l * 2) * 2048 + f * 512;
  const float* z1 = Zp + (size_t)(l * 2 + 1) * 2048 + f * 512;
  const float* w0 = Wp + (size_t)(l * 2) * 2048 + f * 512;
  const float* w1 = Wp + (size_t)(l * 2 + 1) * 2048 + f * 512;
  float b = bdp[0];
  float s = 0.f;
  #pragma unroll
  for (int k = 0; k < 8; ++k){
    int si = lane + k * 64;
    float z = z0[si] + z1[si];
    float w = w0[si] + w1[si];
    s = fmaf(w / z + b, wlp[si], s);
  }
  #pragma unroll
  for (int st = 1; st < 64; st <<= 1)
    s += __shfl_xor(s, st, 64);
  if (lane == 0) out[f * L_ + l] = s + blp[0];
}

// ---------------- K6: accu, term from law (in out) ----------------
__global__ __launch_bounds__(256) void k_at(const float* __restrict__ Wa, const float* __restrict__ ba,
      const float* __restrict__ Wt, const float* __restrict__ bt, float* __restrict__ out){
  int f = blockIdx.x, tid = threadIdx.x;
  __shared__ float lawf[L_];
  if (tid < L_) lawf[tid] = out[f * L_ + tid];
  __syncthreads();
  if (tid < NACCU){
    float s = ba[tid];
    for (int ll = 0; ll < L_; ++ll) s = fmaf(lawf[ll], Wa[tid * L_ + ll], s);
    out[F_ * L_ + f * NACCU + tid] = s;
  }
  if (tid >= 128 && tid < 128 + NTERM){
    int t = tid - 128;
    float s = bt[t];
    for (int ll = 0; ll < L_; ++ll) s = fmaf(lawf[ll], Wt[t * L_ + ll], s);
    out[F_ * L_ + F_ * NACCU + f * NTERM + t] = s;
  }
}

// ---------------- fallback path (ws too small for Ebf; dead in practice) ----------------
__global__ __launch_bounds__(256) void k_attn_fb(const short* __restrict__ Gb, const float* __restrict__ E,
      const float* __restrict__ vw, const float* __restrict__ cbg,
      const float* __restrict__ bdp, float* __restrict__ dws){
  __shared__ __align__(16) short As[128 * 64];
  __shared__ __align__(16) short Bs[128 * 64];
  __shared__ float mM[2][128], mZ[2][128], mW[2][128];
  int b0 = blockIdx.x;
  int bid = (b0 & 7) * 206 + (b0 >> 3);
  int l  = bid >> 4;
  int f  = (bid >> 2) & 3;
  int sc = bid & 3;
  int s0 = sc * 128;
  int tid = threadIdx.x, lane = tid & 63, wid = tid >> 6;
  int wr = wid >> 1, wc = wid & 1, ln = lane & 15, lh = lane >> 4;
  const float invsq = 0.03608439182435161f;
  float sm_m[16], sm_z[16], sm_w[16];
  #pragma unroll
  for (int i = 0; i < 16; ++i){ sm_m[i] = -3.0e38f; sm_z[i] = 0.f; sm_w[i] = 0.f; }
  int srow = tid >> 1, hf = tid & 1;
  int swz = srow & 7;
  const short* gp = Gb + (size_t)(f * S_ + s0 + srow) * D_;
  for (int rt = 0; rt < 4; ++rt){
    f32x4 acc[4][4];
    #pragma unroll
    for (int i = 0; i < 4; ++i)
      #pragma unroll
      for (int j = 0; j < 4; ++j)
        acc[i][j] = (f32x4){0.f, 0.f, 0.f, 0.f};
    const float* ep = E + (size_t)(l * R_ + rt * 128 + srow) * D_;
    for (int k0 = 0; k0 < D_; k0 += 64){
      #pragma unroll
      for (int q = 0; q < 4; ++q){
        int k = hf * 32 + q * 8;
        short8 v = *reinterpret_cast<const short8*>(&gp[k0 + k]);
        *reinterpret_cast<short8*>(&As[srow * 64 + k]) = v;
      }
      #pragma unroll
      for (int q = 0; q < 4; ++q){
        int k = hf * 32 + q * 8;
        float4 v0 = *reinterpret_cast<const float4*>(&ep[k0 + k]);
        float4 v1 = *reinterpret_cast<const float4*>(&ep[k0 + k + 4]);
        short8 p;
        p[0] = f2bf(v0.x); p[1] = f2bf(v0.y); p[2] = f2bf(v0.z); p[3] = f2bf(v0.w);
        p[4] = f2bf(v1.x); p[5] = f2bf(v1.y); p[6] = f2bf(v1.z); p[7] = f2bf(v1.w);
        *reinterpret_cast<short8*>(&Bs[srow * 64 + (((k >> 3) ^ swz) * 8)]) = p;
      }
      __syncthreads();
      mfma_tile(As, Bs, acc, wr, wc, ln, lh);
      __syncthreads();
    }
    float vwv[4], cbl[4];
    #pragma unroll
    for (int j = 0; j < 4; ++j){
      int r = l * R_ + rt * 128 + wc * 64 + j * 16 + ln;
      vwv[j] = vw[r];
      cbl[j] = cbg[r];
    }
    #pragma unroll
    for (int i = 0; i < 4; ++i){
      #pragma unroll
      for (int rg = 0; rg < 4; ++rg){
        float v0 = fmaf(acc[i][0][rg], invsq, cbl[0]);
        float v1 = fmaf(acc[i][1][rg], invsq, cbl[1]);
        float v2 = fmaf(acc[i][2][rg], invsq, cbl[2]);
        float v3 = fmaf(acc[i][3][rg], invsq, cbl[3]);
        float tm = fmaxf(fmaxf(v0, v1), fmaxf(v2, v3));
        int idx = i * 4 + rg;
        float mo = sm_m[idx];
        float nm = fmaxf(mo, tm);
        float scl = __expf(mo - nm);
        float p0 = __expf(v0 - nm), p1 = __expf(v1 - nm);
        float p2 = __expf(v2 - nm), p3 = __expf(v3 - nm);
        sm_z[idx] = fmaf(sm_z[idx], scl, (p0 + p1) + (p2 + p3));
        sm_w[idx] = fmaf(sm_w[idx], scl, fmaf(p0, vwv[0], fmaf(p1, vwv[1], fmaf(p2, vwv[2], p3 * vwv[3]))));
        sm_m[idx] = nm;
      }
    }
  }
  #pragma unroll
  for (int st = 1; st < 16; st <<= 1){
    #pragma unroll
    for (int idx = 0; idx < 16; ++idx){
      float om = __shfl_xor(sm_m[idx], st, 64);
      float oz = __shfl_xor(sm_z[idx], st, 64);
      float ow = __shfl_xor(sm_w[idx], st, 64);
      float nm = fmaxf(sm_m[idx], om);
      float e1 = __expf(sm_m[idx] - nm);
      float e2 = __expf(om - nm);
      sm_z[idx] = fmaf(sm_z[idx], e1, oz * e2);
      sm_w[idx] = fmaf(sm_w[idx], e1, ow * e2);
      sm_m[idx] = nm;
    }
  }
  if (ln == 0){
    #pragma unroll
    for (int i = 0; i < 4; ++i)
      #pragma unroll
      for (int rg = 0; rg < 4; ++rg){
        int row = wr * 64 + i * 16 + lh * 4 + rg;
        int idx = i * 4 + rg;
        mM[wc][row] = sm_m[idx]; mZ[wc][row] = sm_z[idx]; mW[wc][row] = sm_w[idx];
      }
  }
  __syncthreads();
  if (tid < 128){
    float ma = mM[0][tid], mb = mM[1][tid];
    float nm = fmaxf(ma, mb);
    float ea = __expf(ma - nm), eb = __expf(mb - nm);
    float z = mZ[0][tid] * ea + mZ[1][tid] * eb;
    float w = mW[0][tid] * ea + mW[1][tid] * eb;
    dws[(size_t)(f * L_ + l) * S_ + s0 + tid] = w / z + bdp[0];
  }
}

__global__ __launch_bounds__(256) void k_final(const float* __restrict__ dws, const float* __restrict__ wlp,
      const float* __restrict__ blp, const float* __restrict__ Wa, const float* __restrict__ ba,
      const float* __restrict__ Wt, const float* __restrict__ bt, float* __restrict__ out){
  int f = blockIdx.x, tid = threadIdx.x;
  __shared__ float lawf[L_];
  if (tid < L_){
    const float* dp = dws + (size_t)(f * L_ + tid) * S_;
    float s = 0.f;
    #pragma unroll 4
    for (int i = 0; i < S_; i += 4){
      float4 v  = *reinterpret_cast<const float4*>(&dp[i]);
      float4 wv = *reinterpret_cast<const float4*>(&wlp[i]);
      s = fmaf(v.x, wv.x, fmaf(v.y, wv.y, fmaf(v.z, wv.z, fmaf(v.w, wv.w, s))));
    }
    s += blp[0];
    out[f * L_ + tid] = s;
    lawf[tid] = s;
  }
  __syncthreads();
  if (tid < NACCU){
    float s = ba[tid];
    for (int ll = 0; ll < L_; ++ll) s = fmaf(lawf[ll], Wa[tid * L_ + ll], s);
    out[F_ * L_ + f * NACCU + tid] = s;
  }
  if (tid >= 128 && tid < 128 + NTERM){
    int t = tid - 128;
    float s = bt[t];
    for (int ll = 0; ll < L_; ++ll) s = fmaf(lawf[ll], Wt[t * L_ + ll], s);
    out[F_ * L_ + F_ * NACCU + f * NTERM + t] = s;
  }
}

extern "C" void kernel_launch(void* const* d_in, const int* in_sizes, int n_in,
                              void* d_out, int out_size, void* d_ws, size_t ws_size,
                              hipStream_t stream){
  (void)in_sizes; (void)n_in; (void)out_size;
  const float* fact = (const float*)d_in[0];
  const float* E    = (const float*)d_in[1];
  const float* Wq   = (const float*)d_in[2];
  const float* bq   = (const float*)d_in[3];
  const float* Wk   = (const float*)d_in[4];
  const float* bk   = (const float*)d_in[5];
  const float* Wv   = (const float*)d_in[6];
  const float* bv   = (const float*)d_in[7];
  const float* wd   = (const float*)d_in[8];
  const float* bdp  = (const float*)d_in[9];
  const float* wlp  = (const float*)d_in[10];
  const float* blp  = (const float*)d_in[11];
  const float* Wa   = (const float*)d_in[12];
  const float* ba   = (const float*)d_in[13];
  const float* Wt   = (const float*)d_in[14];
  const float* bt   = (const float*)d_in[15];
  const float* mask = (const float*)d_in[16];
  (void)bk;
  char* ws = (char*)d_ws;
  float* u   = (float*)(ws + 0);
  float* v2  = (float*)(ws + 3072);
  float* cw  = (float*)(ws + 6144);
  short* Mt  = (short*)(ws + 6400);
  short* Gb  = (short*)(ws + 1186048);
  float* vw  = (float*)(ws + 4331776);
  float* cb  = (float*)(ws + 4542720);
  float* dws = (float*)(ws + 4753664);
  short* Ebf = (short*)(ws + 5597440);
  float* Zp  = (float*)(ws + 86599936);
  float* Wp  = (float*)(ws + 88287488);
  const size_t need2 = 89975040ULL;
  bool pre = ws_size >= need2;
  float* out = (float*)d_out;

  k_front<<<dim3(40), dim3(256), 0, stream>>>(Wk, Wq, Mt, Wv, wd, bq, bv, u, v2, cw);
  k_mid<<<dim3(920), dim3(256), 0, stream>>>(fact, Mt, Gb, E, u, v2, cw, mask, vw, cb,
                                             pre ? Ebf : (short*)nullptr);
  if (pre){
    k_attn8<<<dim3(1648), dim3(512), 0, stream>>>(Gb, Ebf, vw, cb, Zp, Wp);
    k_law<<<dim3(L_), dim3(256), 0, stream>>>(Zp, Wp, bdp, wlp, blp, out);
    k_at<<<dim3(4), dim3(256), 0, stream>>>(Wa, ba, Wt, bt, out);
  } else {
    k_attn_fb<<<dim3(1648), dim3(256), 0, stream>>>(Gb, E, vw, cb, bdp, dws);
    k_final<<<dim3(4), dim3(256), 0, stream>>>(dws, wlp, blp, Wa, ba, Wt, bt, out);
  }
}